// Round 4
// baseline (3247.437 us; speedup 1.0000x reference)
//
#include <hip/hip_runtime.h>
#include <hip/hip_bf16.h>

#define NREL 14
#define NE   100000
#define NN   100000
#define EPF  800000
#define NKV  360000   // sum of src-range sizes over relations
#define NQ   370000   // sum of dst-range sizes over relations
#define MAXR 40000    // largest type-range size (type 2)

__device__ __constant__ int d_slo[NREL]   = {0,0,0,10000,10000,30000,10000,30000,70000,30000,70000,10000,30000,70000};
__device__ __constant__ int d_dlo[NREL]   = {10000,30000,70000,30000,70000,70000,0,0,0,10000,30000,10000,30000,70000};
__device__ __constant__ int d_koff[NREL+1]= {0,10000,20000,30000,50000,70000,110000,130000,170000,200000,240000,270000,290000,330000,360000};
__device__ __constant__ int d_qoff[NREL+1]= {0,20000,60000,90000,130000,160000,190000,200000,210000,220000,240000,280000,300000,340000,370000};
__device__ __constant__ int d_trel[4][4]  = {{6,7,8,-1},{0,9,11,-1},{1,3,10,12},{2,4,5,13}};
__device__ __constant__ int d_ntrel[4]    = {3,3,4,4};

// host copies for the per-relation fallback loop
static const int h_slo[NREL] = {0,0,0,10000,10000,30000,10000,30000,70000,30000,70000,10000,30000,70000};
static const int h_dlo[NREL] = {10000,30000,70000,30000,70000,70000,0,0,0,10000,30000,10000,30000,70000};
static const int h_ns [NREL] = {10000,10000,10000,20000,20000,40000,20000,40000,30000,40000,30000,20000,40000,30000};
static const int h_nd [NREL] = {20000,40000,30000,40000,30000,30000,10000,10000,10000,20000,40000,20000,40000,30000};

__device__ __forceinline__ int fenc(float f) {
    int i = __float_as_int(f);
    return i < 0 ? (i ^ 0x7fffffff) : i;
}
__device__ __forceinline__ float fdec(int k) {
    return __int_as_float(k < 0 ? (k ^ 0x7fffffff) : k);
}
__device__ __forceinline__ float csig(float v, float lo, float hi) {
    float mid = 0.5f * (lo + hi);
    float s = 1.0f / (1.0f + expf(-0.1f * (v - mid)));
    return (s - 0.5f) * (hi - lo) + mid;
}

// ============================ PRIMARY PATH ==================================
// ---- Kernel A: per-(rel,node) K,V (src ranges) and Q (dst ranges) ----------
template<int DIN>
__global__ __launch_bounds__(256) void node_kvq(
    const float* __restrict__ h,
    const float* __restrict__ Wk, const float* __restrict__ bk,
    const float* __restrict__ Wv, const float* __restrict__ bv,
    const float* __restrict__ Wq, const float* __restrict__ bq,
    float* __restrict__ Kb, float* __restrict__ Vb, float* __restrict__ Qb)
{
    int wid  = (blockIdx.x * blockDim.x + threadIdx.x) >> 6;
    int lane = threadIdx.x & 63;
    if (wid < NKV) {
        int r = 0;
        while (r < NREL - 1 && wid >= d_koff[r + 1]) ++r;
        int node = d_slo[r] + (wid - d_koff[r]);
        const float* hrow = h + (long)node * DIN;
        const float* wk = Wk + r * DIN * 64;
        const float* wv = Wv + r * DIN * 64;
        float k = bk[r * 64 + lane];
        float v = bv[r * 64 + lane];
        #pragma unroll 4
        for (int j = 0; j < DIN; ++j) {
            float hv = hrow[j];
            k = fmaf(hv, wk[j * 64 + lane], k);
            v = fmaf(hv, wv[j * 64 + lane], v);
        }
        Kb[(long)wid * 64 + lane] = k;
        Vb[(long)wid * 64 + lane] = v;
    } else if (wid < NKV + NQ) {
        int qrow = wid - NKV;
        int r = 0;
        while (r < NREL - 1 && qrow >= d_qoff[r + 1]) ++r;
        int node = d_dlo[r] + (qrow - d_qoff[r]);
        const float* hrow = h + (long)node * DIN;
        const float* wq = Wq + r * DIN * 64;
        float qa = bq[r * 64 + lane];
        #pragma unroll 4
        for (int j = 0; j < DIN; ++j) qa = fmaf(hrow[j], wq[j * 64 + lane], qa);
        Qb[(long)qrow * 64 + lane] = qa;
    }
}

// ---- Kernel A2: skip connection  acc[n] = sum_r(dst=type(n)) h[n]@Ws[r]+bs[r]
template<int DIN>
__global__ __launch_bounds__(256) void self_skip(
    const float* __restrict__ h, const float* __restrict__ Ws,
    const float* __restrict__ bs, float* __restrict__ acc)
{
    int wid  = (blockIdx.x * blockDim.x + threadIdx.x) >> 6;
    int lane = threadIdx.x & 63;
    if (wid >= NN) return;
    int node = wid;
    int t = node < 10000 ? 0 : node < 30000 ? 1 : node < 70000 ? 2 : 3;
    const float* hrow = h + (long)node * DIN;
    float a = 0.f;
    int nr = d_ntrel[t];
    for (int ri = 0; ri < nr; ++ri) {
        int r = d_trel[t][ri];
        a += bs[r * 64 + lane];
        const float* w = Ws + r * DIN * 64;
        #pragma unroll 4
        for (int j = 0; j < DIN; ++j) a = fmaf(hrow[j], w[j * 64 + lane], a);
    }
    acc[(long)node * 64 + lane] = a;
}

// ---- Kernel B: alpha per edge + segment max --------------------------------
__global__ __launch_bounds__(256) void edge_alpha(
    const float* __restrict__ Kb, const float* __restrict__ Qb,
    const int* __restrict__ esrc, const int* __restrict__ edst,
    const float* __restrict__ eattr, const float* __restrict__ We,
    float* __restrict__ alphab, int* __restrict__ mbuf)
{
    int wid  = (blockIdx.x * blockDim.x + threadIdx.x) >> 6;
    int lane = threadIdx.x & 63;
    if (wid >= NREL * NE) return;
    int r = wid / NE;
    int s = esrc[wid], d = edst[wid];
    float ea0 = eattr[2 * (long)wid], ea1 = eattr[2 * (long)wid + 1];
    float eemb = ea0 * We[r * 128 + lane] + ea1 * We[r * 128 + 64 + lane];
    float kv = Kb[((long)(d_koff[r] + s - d_slo[r])) * 64 + lane] + eemb;
    float qv = Qb[((long)(d_qoff[r] + d - d_dlo[r])) * 64 + lane];
    float p = qv * kv;
    #pragma unroll
    for (int m = 32; m > 0; m >>= 1) p += __shfl_xor(p, m);
    if (lane == 0) {
        float alpha = p * 0.125f;
        alphab[wid] = alpha;
        atomicMax(&mbuf[d_qoff[r] + d - d_dlo[r]], fenc(alpha));
    }
}

// ---- Kernel C: a = exp(alpha - m), den += a --------------------------------
__global__ __launch_bounds__(256) void edge_expden(
    const int* __restrict__ edst, float* __restrict__ alphab,
    const int* __restrict__ mbuf, float* __restrict__ den)
{
    int tid = blockIdx.x * blockDim.x + threadIdx.x;
    if (tid >= NREL * NE) return;
    int r = tid / NE;
    int d = edst[tid];
    int idx = d_qoff[r] + d - d_dlo[r];
    float m = fdec(mbuf[idx]);
    float a = expf(alphab[tid] - m);
    alphab[tid] = a;
    atomicAdd(&den[idx], a);
}

// ---- Kernel D: acc[d] += (a/den) * (V[s] + eemb) ---------------------------
__global__ __launch_bounds__(256) void edge_scatter(
    const float* __restrict__ Vb,
    const int* __restrict__ esrc, const int* __restrict__ edst,
    const float* __restrict__ eattr, const float* __restrict__ We,
    const float* __restrict__ alphab, const float* __restrict__ den,
    float* __restrict__ acc)
{
    int wid  = (blockIdx.x * blockDim.x + threadIdx.x) >> 6;
    int lane = threadIdx.x & 63;
    if (wid >= NREL * NE) return;
    int r = wid / NE;
    int s = esrc[wid], d = edst[wid];
    int idx = d_qoff[r] + d - d_dlo[r];
    float w = alphab[wid] / (den[idx] + 1e-16f);
    float ea0 = eattr[2 * (long)wid], ea1 = eattr[2 * (long)wid + 1];
    float eemb = ea0 * We[r * 128 + lane] + ea1 * We[r * 128 + 64 + lane];
    float v = Vb[((long)(d_koff[r] + s - d_slo[r])) * 64 + lane] + eemb;
    atomicAdd(&acc[(long)d * 64 + lane], w * v);
}

// ========================= PER-RELATION FALLBACK ============================
template<int DIN>
__global__ __launch_bounds__(256) void node_kvq_r(
    const float* __restrict__ h,
    const float* __restrict__ Wk, const float* __restrict__ bk,
    const float* __restrict__ Wv, const float* __restrict__ bv,
    const float* __restrict__ Wq, const float* __restrict__ bq,
    float* __restrict__ Kb, float* __restrict__ Vb, float* __restrict__ Qb,
    int r, int slo, int ns, int dlo, int nd)
{
    int wid  = (blockIdx.x * blockDim.x + threadIdx.x) >> 6;
    int lane = threadIdx.x & 63;
    if (wid < ns) {
        const float* hrow = h + (long)(slo + wid) * DIN;
        const float* wk = Wk + r * DIN * 64;
        const float* wv = Wv + r * DIN * 64;
        float k = bk[r * 64 + lane];
        float v = bv[r * 64 + lane];
        #pragma unroll 4
        for (int j = 0; j < DIN; ++j) {
            float hv = hrow[j];
            k = fmaf(hv, wk[j * 64 + lane], k);
            v = fmaf(hv, wv[j * 64 + lane], v);
        }
        Kb[(long)wid * 64 + lane] = k;
        Vb[(long)wid * 64 + lane] = v;
    } else if (wid < ns + nd) {
        int q = wid - ns;
        const float* hrow = h + (long)(dlo + q) * DIN;
        const float* wq = Wq + r * DIN * 64;
        float qa = bq[r * 64 + lane];
        #pragma unroll 4
        for (int j = 0; j < DIN; ++j) qa = fmaf(hrow[j], wq[j * 64 + lane], qa);
        Qb[(long)q * 64 + lane] = qa;
    }
}

__global__ __launch_bounds__(256) void edge_alpha_r(
    const float* __restrict__ Kb, const float* __restrict__ Qb,
    const int* __restrict__ esrc, const int* __restrict__ edst,
    const float* __restrict__ eattr, const float* __restrict__ We,
    float* __restrict__ alphab, int* __restrict__ mbuf,
    int r, int slo, int dlo)
{
    int wid  = (blockIdx.x * blockDim.x + threadIdx.x) >> 6;
    int lane = threadIdx.x & 63;
    if (wid >= NE) return;
    long e = (long)r * NE + wid;
    int s = esrc[e], d = edst[e];
    float ea0 = eattr[2 * e], ea1 = eattr[2 * e + 1];
    float eemb = ea0 * We[r * 128 + lane] + ea1 * We[r * 128 + 64 + lane];
    float kv = Kb[(long)(s - slo) * 64 + lane] + eemb;
    float qv = Qb[(long)(d - dlo) * 64 + lane];
    float p = qv * kv;
    #pragma unroll
    for (int m = 32; m > 0; m >>= 1) p += __shfl_xor(p, m);
    if (lane == 0) {
        float alpha = p * 0.125f;
        alphab[wid] = alpha;
        atomicMax(&mbuf[d - dlo], fenc(alpha));
    }
}

__global__ __launch_bounds__(256) void edge_expden_r(
    const int* __restrict__ edst, float* __restrict__ alphab,
    const int* __restrict__ mbuf, float* __restrict__ den,
    int r, int dlo)
{
    int tid = blockIdx.x * blockDim.x + threadIdx.x;
    if (tid >= NE) return;
    int d = edst[(long)r * NE + tid];
    float m = fdec(mbuf[d - dlo]);
    float a = expf(alphab[tid] - m);
    alphab[tid] = a;
    atomicAdd((float*)&den[d - dlo], a);
}

__global__ __launch_bounds__(256) void edge_scatter_r(
    const float* __restrict__ Vb,
    const int* __restrict__ esrc, const int* __restrict__ edst,
    const float* __restrict__ eattr, const float* __restrict__ We,
    const float* __restrict__ alphab, const float* __restrict__ den,
    float* __restrict__ acc, int r, int slo, int dlo)
{
    int wid  = (blockIdx.x * blockDim.x + threadIdx.x) >> 6;
    int lane = threadIdx.x & 63;
    if (wid >= NE) return;
    long e = (long)r * NE + wid;
    int s = esrc[e], d = edst[e];
    float w = alphab[wid] / (den[d - dlo] + 1e-16f);
    float ea0 = eattr[2 * e], ea1 = eattr[2 * e + 1];
    float eemb = ea0 * We[r * 128 + lane] + ea1 * We[r * 128 + 64 + lane];
    float v = Vb[(long)(s - slo) * 64 + lane] + eemb;
    atomicAdd(&acc[(long)d * 64 + lane], w * v);
}

// ============================ SHARED TAIL ===================================
__global__ __launch_bounds__(256) void relu_copy(
    const float* __restrict__ acc, float* __restrict__ h1, int n)
{
    int tid = blockIdx.x * blockDim.x + threadIdx.x;
    if (tid < n) h1[tid] = fmaxf(acc[tid], 0.f);
}

__global__ __launch_bounds__(256) void head(
    const float* __restrict__ acc, const float* __restrict__ Wlin,
    float* __restrict__ out4)
{
    int wid  = (blockIdx.x * blockDim.x + threadIdx.x) >> 6;
    int lane = threadIdx.x & 63;
    if (wid >= NN) return;
    float hv = fmaxf(acc[(long)wid * 64 + lane], 0.f);
    float4 w = ((const float4*)Wlin)[lane];
    float p0 = hv * w.x, p1 = hv * w.y, p2 = hv * w.z, p3 = hv * w.w;
    #pragma unroll
    for (int m = 32; m > 0; m >>= 1) {
        p0 += __shfl_xor(p0, m);
        p1 += __shfl_xor(p1, m);
        p2 += __shfl_xor(p2, m);
        p3 += __shfl_xor(p3, m);
    }
    if (lane == 0) {
        out4[4 * (long)wid + 0] = p0;
        out4[4 * (long)wid + 1] = p1;
        out4[4 * (long)wid + 2] = p2;
        out4[4 * (long)wid + 3] = p3;
    }
}

__global__ __launch_bounds__(256) void pf_accum(
    const int* __restrict__ pfi, const int* __restrict__ pfj,
    const float* __restrict__ pfa, const float* __restrict__ out4,
    float* __restrict__ Pb, float* __restrict__ Qp)
{
    int e = blockIdx.x * blockDim.x + threadIdx.x;
    if (e >= EPF) return;
    int i = pfi[e], j = pfj[e];
    float r = pfa[2 * (long)e], x = pfa[2 * (long)e + 1];
    float dn = r * r + x * x;
    float G = r / dn, B = -x / dn;
    float thi = out4[4 * (long)i + 1], thj = out4[4 * (long)j + 1];
    float Vi = fabsf(out4[4 * (long)i]), Vj = fabsf(out4[4 * (long)j]);
    float dlt = thj - thi;
    float cd = cosf(dlt), sd = sinf(dlt);
    float vv = Vi * Vj;
    atomicAdd(&Pb[i], vv * (G * cd + B * sd));
    atomicAdd(&Qp[i], vv * (G * sd - B * cd));
}

__global__ __launch_bounds__(256) void final_out(
    const float* __restrict__ out4, const float* __restrict__ cons,
    const float* __restrict__ xin, const float* __restrict__ Pb,
    const float* __restrict__ Qp, float* __restrict__ out)
{
    int n = blockIdx.x * blockDim.x + threadIdx.x;
    if (n >= NN) return;
    const float* c = cons + 7 * (long)n;
    float th = out4[4 * (long)n + 1];
    float V  = fabsf(out4[4 * (long)n + 0]);
    float o0 = csig(V, c[0], c[1]) / xin[4 * (long)n + 0];
    float o2 = csig(Pb[n], c[3], c[4]);
    float o3 = csig(Qp[n], c[5], c[6]);
    out[4 * (long)n + 0] = o0;
    out[4 * (long)n + 1] = th;
    out[4 * (long)n + 2] = o2;
    out[4 * (long)n + 3] = o3;
}

extern "C" void kernel_launch(void* const* d_in, const int* in_sizes, int n_in,
                              void* d_out, int out_size, void* d_ws, size_t ws_size,
                              hipStream_t stream) {
    const float* xin  = (const float*)d_in[0];
    const float* cons = (const float*)d_in[1];
    const int*   esrc = (const int*)d_in[2];
    const int*   edst = (const int*)d_in[3];
    const float* eatt = (const float*)d_in[4];
    const int*   pfi  = (const int*)d_in[5];
    const int*   pfj  = (const int*)d_in[6];
    const float* pfa  = (const float*)d_in[7];

    const float* Wlin;
    int wb;
    if (in_sizes[8] == 256) { Wlin = (const float*)d_in[8];  wb = 9; }
    else                    { Wlin = (const float*)d_in[26]; wb = 8; }
    const float* Wq0 = (const float*)d_in[wb + 0];
    const float* bq0 = (const float*)d_in[wb + 1];
    const float* Wk0 = (const float*)d_in[wb + 2];
    const float* bk0 = (const float*)d_in[wb + 3];
    const float* Wv0 = (const float*)d_in[wb + 4];
    const float* bv0 = (const float*)d_in[wb + 5];
    const float* We0 = (const float*)d_in[wb + 6];
    const float* Ws0 = (const float*)d_in[wb + 7];
    const float* bs0 = (const float*)d_in[wb + 8];
    const float* Wq1 = (const float*)d_in[wb + 9];
    const float* bq1 = (const float*)d_in[wb + 10];
    const float* Wk1 = (const float*)d_in[wb + 11];
    const float* bk1 = (const float*)d_in[wb + 12];
    const float* Wv1 = (const float*)d_in[wb + 13];
    const float* bv1 = (const float*)d_in[wb + 14];
    const float* We1 = (const float*)d_in[wb + 15];
    const float* Ws1 = (const float*)d_in[wb + 16];
    const float* bs1 = (const float*)d_in[wb + 17];

    const float* Wq[2] = {Wq0, Wq1}; const float* bq[2] = {bq0, bq1};
    const float* Wk[2] = {Wk0, Wk1}; const float* bk[2] = {bk0, bk1};
    const float* Wv[2] = {Wv0, Wv1}; const float* bv[2] = {bv0, bv1};
    const float* We[2] = {We0, We1};
    const float* Ws[2] = {Ws0, Ws1}; const float* bs[2] = {bs0, bs1};

    // ---- full-batch workspace layout (floats) ----
    size_t fullNeed = ((size_t)NN*64*2 + (size_t)NKV*64*2 + (size_t)NQ*64
                       + (size_t)NREL*NE + NQ*2 + NN*2 + (size_t)NN*4) * 4;

    const int nodeWaveBlocks = (NN + 3) / 4;

    if (ws_size >= fullNeed) {
        // ===================== PRIMARY (full-batch) =====================
        float* w = (float*)d_ws;
        size_t off = 0;
        float* h1     = w + off; off += (size_t)NN * 64;
        float* acc    = w + off; off += (size_t)NN * 64;
        float* Kb     = w + off; off += (size_t)NKV * 64;
        float* Vb     = w + off; off += (size_t)NKV * 64;
        float* Qb     = w + off; off += (size_t)NQ * 64;
        float* alphab = w + off; off += (size_t)NREL * NE;
        int*   mbuf   = (int*)(w + off); off += NQ;
        float* den    = w + off; off += NQ;
        float* Pb     = w + off; off += NN;
        float* Qp     = w + off; off += NN;
        float* out4   = w + off; off += (size_t)NN * 4;

        const int edgeWaveBlocks = (NREL * NE + 3) / 4;
        const int kvqBlocks      = (NKV + NQ + 3) / 4;

        hipMemsetAsync(mbuf, 0x80, (size_t)NQ * 4, stream);
        hipMemsetAsync(den,  0,    (size_t)NQ * 4, stream);
        hipMemsetAsync(Pb,   0,    (size_t)NN * 4, stream);
        hipMemsetAsync(Qp,   0,    (size_t)NN * 4, stream);

        node_kvq<4><<<kvqBlocks, 256, 0, stream>>>(xin, Wk0, bk0, Wv0, bv0, Wq0, bq0, Kb, Vb, Qb);
        self_skip<4><<<nodeWaveBlocks, 256, 0, stream>>>(xin, Ws0, bs0, acc);
        edge_alpha<<<edgeWaveBlocks, 256, 0, stream>>>(Kb, Qb, esrc, edst, eatt, We0, alphab, mbuf);
        edge_expden<<<(NREL * NE + 255) / 256, 256, 0, stream>>>(edst, alphab, mbuf, den);
        edge_scatter<<<edgeWaveBlocks, 256, 0, stream>>>(Vb, esrc, edst, eatt, We0, alphab, den, acc);
        relu_copy<<<(NN * 64 + 255) / 256, 256, 0, stream>>>(acc, h1, NN * 64);

        hipMemsetAsync(mbuf, 0x80, (size_t)NQ * 4, stream);
        hipMemsetAsync(den,  0,    (size_t)NQ * 4, stream);

        node_kvq<64><<<kvqBlocks, 256, 0, stream>>>(h1, Wk1, bk1, Wv1, bv1, Wq1, bq1, Kb, Vb, Qb);
        self_skip<64><<<nodeWaveBlocks, 256, 0, stream>>>(h1, Ws1, bs1, acc);
        edge_alpha<<<edgeWaveBlocks, 256, 0, stream>>>(Kb, Qb, esrc, edst, eatt, We1, alphab, mbuf);
        edge_expden<<<(NREL * NE + 255) / 256, 256, 0, stream>>>(edst, alphab, mbuf, den);
        edge_scatter<<<edgeWaveBlocks, 256, 0, stream>>>(Vb, esrc, edst, eatt, We1, alphab, den, acc);

        head<<<nodeWaveBlocks, 256, 0, stream>>>(acc, Wlin, out4);
        pf_accum<<<(EPF + 255) / 256, 256, 0, stream>>>(pfi, pfj, pfa, out4, Pb, Qp);
        final_out<<<(NN + 255) / 256, 256, 0, stream>>>(out4, cons, xin, Pb, Qp, (float*)d_out);
    } else {
        // ===================== FALLBACK (per-relation) =====================
        float* w = (float*)d_ws;
        size_t off = 0;
        float* h1     = w + off; off += (size_t)NN * 64;      // 25.6 MB
        float* acc    = w + off; off += (size_t)NN * 64;      // 25.6 MB
        float* Kb     = w + off; off += (size_t)MAXR * 64;    // 10.24 MB
        float* Vb     = w + off; off += (size_t)MAXR * 64;    // 10.24 MB
        float* Qb     = w + off; off += (size_t)MAXR * 64;    // 10.24 MB
        float* alphab = w + off; off += NE;                   // 0.4 MB
        int*   mbuf   = (int*)(w + off); off += MAXR;
        float* den    = w + off; off += MAXR;
        float* Pb     = w + off; off += NN;
        float* Qp     = w + off; off += NN;
        float* out4   = w + off; off += (size_t)NN * 4;
        if (ws_size < off * sizeof(float)) return;            // truly can't run

        hipMemsetAsync(Pb, 0, (size_t)NN * 4, stream);
        hipMemsetAsync(Qp, 0, (size_t)NN * 4, stream);

        for (int layer = 0; layer < 2; ++layer) {
            const float* h = layer == 0 ? xin : h1;
            if (layer == 0)
                self_skip<4><<<nodeWaveBlocks, 256, 0, stream>>>(xin, Ws0, bs0, acc);
            else
                self_skip<64><<<nodeWaveBlocks, 256, 0, stream>>>(h1, Ws1, bs1, acc);
            for (int r = 0; r < NREL; ++r) {
                int slo = h_slo[r], ns = h_ns[r], dlo = h_dlo[r], nd = h_nd[r];
                hipMemsetAsync(mbuf, 0x80, (size_t)nd * 4, stream);
                hipMemsetAsync(den,  0,    (size_t)nd * 4, stream);
                int kvqB = (ns + nd + 3) / 4;
                if (layer == 0)
                    node_kvq_r<4><<<kvqB, 256, 0, stream>>>(h, Wk[0], bk[0], Wv[0], bv[0], Wq[0], bq[0], Kb, Vb, Qb, r, slo, ns, dlo, nd);
                else
                    node_kvq_r<64><<<kvqB, 256, 0, stream>>>(h, Wk[1], bk[1], Wv[1], bv[1], Wq[1], bq[1], Kb, Vb, Qb, r, slo, ns, dlo, nd);
                edge_alpha_r<<<(NE + 3) / 4, 256, 0, stream>>>(Kb, Qb, esrc, edst, eatt, We[layer], alphab, mbuf, r, slo, dlo);
                edge_expden_r<<<(NE + 255) / 256, 256, 0, stream>>>(edst, alphab, mbuf, den, r, dlo);
                edge_scatter_r<<<(NE + 3) / 4, 256, 0, stream>>>(Vb, esrc, edst, eatt, We[layer], alphab, den, acc, r, slo, dlo);
            }
            if (layer == 0)
                relu_copy<<<(NN * 64 + 255) / 256, 256, 0, stream>>>(acc, h1, NN * 64);
        }

        head<<<nodeWaveBlocks, 256, 0, stream>>>(acc, Wlin, out4);
        pf_accum<<<(EPF + 255) / 256, 256, 0, stream>>>(pfi, pfj, pfa, out4, Pb, Qp);
        final_out<<<(NN + 255) / 256, 256, 0, stream>>>(out4, cons, xin, Pb, Qp, (float*)d_out);
    }
}

// Round 7
// 2447.758 us; speedup vs baseline: 1.3267x; 1.3267x over previous
//
#include <hip/hip_runtime.h>
#include <hip/hip_bf16.h>

#define NREL 14
#define NE   100000
#define NEDGE (NREL*NE)
#define NN   100000
#define EPF  800000
#define NKV  360000   // sum of src-range sizes over relations
#define NQ   370000   // sum of dst-range sizes over relations
#define NB1  ((NQ + 1023) / 1024)   // scan blocks = 362

__device__ __constant__ int d_slo[NREL]   = {0,0,0,10000,10000,30000,10000,30000,70000,30000,70000,10000,30000,70000};
__device__ __constant__ int d_dlo[NREL]   = {10000,30000,70000,30000,70000,70000,0,0,0,10000,30000,10000,30000,70000};
__device__ __constant__ int d_koff[NREL+1]= {0,10000,20000,30000,50000,70000,110000,130000,170000,200000,240000,270000,290000,330000,360000};
__device__ __constant__ int d_qoff[NREL+1]= {0,20000,60000,90000,130000,160000,190000,200000,210000,220000,240000,280000,300000,340000,370000};
__device__ __constant__ int d_trel[4][4]  = {{6,7,8,-1},{0,9,11,-1},{1,3,10,12},{2,4,5,13}};
__device__ __constant__ int d_ntrel[4]    = {3,3,4,4};

__device__ __forceinline__ float csig(float v, float lo, float hi) {
    float mid = 0.5f * (lo + hi);
    float s = 1.0f / (1.0f + expf(-0.1f * (v - mid)));
    return (s - 0.5f) * (hi - lo) + mid;
}

// ---- combined skip weights: Wc[t] = sum_{r: dst_type==t} Ws[r] -------------
template<int DIN>
__global__ __launch_bounds__(256) void combine_skip(
    const float* __restrict__ Ws, float* __restrict__ Wc)
{
    int tid = blockIdx.x * blockDim.x + threadIdx.x;
    if (tid >= 4 * DIN * 64) return;
    int t = tid / (DIN * 64), o = tid % (DIN * 64);
    float s = 0.f;
    for (int ri = 0; ri < d_ntrel[t]; ++ri) s += Ws[d_trel[t][ri] * DIN * 64 + o];
    Wc[tid] = s;
}

// ---- multi-row K (src rows) + Q (dst rows); 16 rows/wave -------------------
template<int DIN>
__global__ __launch_bounds__(256) void kq_mr(
    const float* __restrict__ h,
    const float* __restrict__ Wk, const float* __restrict__ bk,
    const float* __restrict__ Wq, const float* __restrict__ bq,
    float* __restrict__ Kb, float* __restrict__ Qb)
{
    const int NKVW = NKV / 16, NQW = NQ / 16;
    int wid  = (blockIdx.x * blockDim.x + threadIdx.x) >> 6;
    int lane = threadIdx.x & 63;
    if (wid < NKVW) {
        int rowbase = wid * 16;
        int r = 0;
        while (r < NREL - 1 && rowbase >= d_koff[r + 1]) ++r;
        int node0 = d_slo[r] + (rowbase - d_koff[r]);
        float ak[16];
        float bkv = bk[r * 64 + lane];
        #pragma unroll
        for (int i = 0; i < 16; ++i) ak[i] = bkv;
        const float* wkp = Wk + (long)r * DIN * 64;
        if (DIN == 4) {
            float hv = h[(long)node0 * 4 + lane];   // 16 rows x 4 dims
            #pragma unroll
            for (int j = 0; j < 4; ++j) {
                float wk = wkp[j * 64 + lane];
                #pragma unroll
                for (int i = 0; i < 16; ++i) ak[i] = fmaf(__shfl(hv, i * 4 + j), wk, ak[i]);
            }
        } else {
            float hv[16];
            #pragma unroll
            for (int i = 0; i < 16; ++i) hv[i] = h[(long)(node0 + i) * 64 + lane];
            for (int j = 0; j < 64; ++j) {
                float wk = wkp[j * 64 + lane];
                #pragma unroll
                for (int i = 0; i < 16; ++i) ak[i] = fmaf(__shfl(hv[i], j), wk, ak[i]);
            }
        }
        #pragma unroll
        for (int i = 0; i < 16; ++i) Kb[(long)(rowbase + i) * 64 + lane] = ak[i];
    } else if (wid < NKVW + NQW) {
        int rowbase = (wid - NKVW) * 16;
        int r = 0;
        while (r < NREL - 1 && rowbase >= d_qoff[r + 1]) ++r;
        int node0 = d_dlo[r] + (rowbase - d_qoff[r]);
        float aq[16];
        float bqv = bq[r * 64 + lane];
        #pragma unroll
        for (int i = 0; i < 16; ++i) aq[i] = bqv;
        const float* wqp = Wq + (long)r * DIN * 64;
        if (DIN == 4) {
            float hv = h[(long)node0 * 4 + lane];
            #pragma unroll
            for (int j = 0; j < 4; ++j) {
                float wq = wqp[j * 64 + lane];
                #pragma unroll
                for (int i = 0; i < 16; ++i) aq[i] = fmaf(__shfl(hv, i * 4 + j), wq, aq[i]);
            }
        } else {
            float hv[16];
            #pragma unroll
            for (int i = 0; i < 16; ++i) hv[i] = h[(long)(node0 + i) * 64 + lane];
            for (int j = 0; j < 64; ++j) {
                float wq = wqp[j * 64 + lane];
                #pragma unroll
                for (int i = 0; i < 16; ++i) aq[i] = fmaf(__shfl(hv[i], j), wq, aq[i]);
            }
        }
        #pragma unroll
        for (int i = 0; i < 16; ++i) Qb[(long)(rowbase + i) * 64 + lane] = aq[i];
    }
}

// ---- multi-row V (src rows), overwrites the K buffer after edge_alpha ------
template<int DIN>
__global__ __launch_bounds__(256) void v_mr(
    const float* __restrict__ h,
    const float* __restrict__ Wv, const float* __restrict__ bv,
    float* __restrict__ Vb)
{
    int wid  = (blockIdx.x * blockDim.x + threadIdx.x) >> 6;
    int lane = threadIdx.x & 63;
    if (wid >= NKV / 16) return;
    int rowbase = wid * 16;
    int r = 0;
    while (r < NREL - 1 && rowbase >= d_koff[r + 1]) ++r;
    int node0 = d_slo[r] + (rowbase - d_koff[r]);
    float av[16];
    float bvv = bv[r * 64 + lane];
    #pragma unroll
    for (int i = 0; i < 16; ++i) av[i] = bvv;
    const float* wvp = Wv + (long)r * DIN * 64;
    if (DIN == 4) {
        float hv = h[(long)node0 * 4 + lane];
        #pragma unroll
        for (int j = 0; j < 4; ++j) {
            float wv = wvp[j * 64 + lane];
            #pragma unroll
            for (int i = 0; i < 16; ++i) av[i] = fmaf(__shfl(hv, i * 4 + j), wv, av[i]);
        }
    } else {
        float hv[16];
        #pragma unroll
        for (int i = 0; i < 16; ++i) hv[i] = h[(long)(node0 + i) * 64 + lane];
        for (int j = 0; j < 64; ++j) {
            float wv = wvp[j * 64 + lane];
            #pragma unroll
            for (int i = 0; i < 16; ++i) av[i] = fmaf(__shfl(hv[i], j), wv, av[i]);
        }
    }
    #pragma unroll
    for (int i = 0; i < 16; ++i) Vb[(long)(rowbase + i) * 64 + lane] = av[i];
}

// ---- multi-row skip with combined per-type weights -------------------------
template<int DIN>
__global__ __launch_bounds__(256) void skip_mr(
    const float* __restrict__ h, const float* __restrict__ Wc,
    const float* __restrict__ bs, float* __restrict__ acc)
{
    int wid  = (blockIdx.x * blockDim.x + threadIdx.x) >> 6;
    int lane = threadIdx.x & 63;
    if (wid >= NN / 16) return;
    int node0 = wid * 16;
    int t = node0 < 10000 ? 0 : node0 < 30000 ? 1 : node0 < 70000 ? 2 : 3;
    float bsum = 0.f;
    for (int ri = 0; ri < d_ntrel[t]; ++ri) bsum += bs[d_trel[t][ri] * 64 + lane];
    float a[16];
    #pragma unroll
    for (int i = 0; i < 16; ++i) a[i] = bsum;
    const float* wp = Wc + (long)t * DIN * 64;
    if (DIN == 4) {
        float hv = h[(long)node0 * 4 + lane];
        #pragma unroll
        for (int j = 0; j < 4; ++j) {
            float w = wp[j * 64 + lane];
            #pragma unroll
            for (int i = 0; i < 16; ++i) a[i] = fmaf(__shfl(hv, i * 4 + j), w, a[i]);
        }
    } else {
        float hv[16];
        #pragma unroll
        for (int i = 0; i < 16; ++i) hv[i] = h[(long)(node0 + i) * 64 + lane];
        for (int j = 0; j < 64; ++j) {
            float w = wp[j * 64 + lane];
            #pragma unroll
            for (int i = 0; i < 16; ++i) a[i] = fmaf(__shfl(hv[i], j), w, a[i]);
        }
    }
    #pragma unroll
    for (int i = 0; i < 16; ++i) acc[(long)(node0 + i) * 64 + lane] = a[i];
}

// ---- CSR build: cur doubles as count buffer then fill cursor ---------------
__global__ __launch_bounds__(256) void csr_count(
    const int* __restrict__ edst, int* __restrict__ cur)
{
    int tid = blockIdx.x * blockDim.x + threadIdx.x;
    if (tid >= NEDGE) return;
    int r = tid / NE;
    atomicAdd(&cur[d_qoff[r] + edst[tid] - d_dlo[r]], 1);
}

// inclusive block scan of cur -> rowst[g+1]; bsum[b] = block total
__global__ __launch_bounds__(1024) void scan1(
    const int* __restrict__ cur, int* __restrict__ rowst, int* __restrict__ bsum)
{
    __shared__ int s[1024];
    int t = threadIdx.x, g = blockIdx.x * 1024 + t;
    s[t] = g < NQ ? cur[g] : 0;
    __syncthreads();
    for (int o = 1; o < 1024; o <<= 1) {
        int x = t >= o ? s[t - o] : 0;
        __syncthreads();
        s[t] += x;
        __syncthreads();
    }
    if (g < NQ) rowst[g + 1] = s[t];
    if (t == 1023) bsum[blockIdx.x] = s[1023];
}

__global__ __launch_bounds__(512) void scan2(int* __restrict__ bsum)
{
    __shared__ int s[512];
    int t = threadIdx.x;
    s[t] = t < NB1 ? bsum[t] : 0;
    __syncthreads();
    for (int o = 1; o < 512; o <<= 1) {
        int x = t >= o ? s[t - o] : 0;
        __syncthreads();
        s[t] += x;
        __syncthreads();
    }
    if (t < NB1) bsum[t] = (t == 0) ? 0 : s[t - 1];   // exclusive block offsets
}

__global__ __launch_bounds__(256) void scan3(
    const int* __restrict__ bsum, int* __restrict__ rowst)
{
    int g = blockIdx.x * blockDim.x + threadIdx.x;
    if (g == 0) rowst[0] = 0;
    if (g < NQ) rowst[g + 1] += bsum[g >> 10];
}

__global__ __launch_bounds__(256) void csr_fill(
    const int* __restrict__ edst, const int* __restrict__ rowst,
    int* __restrict__ cur, int* __restrict__ elist)
{
    int tid = blockIdx.x * blockDim.x + threadIdx.x;
    if (tid >= NEDGE) return;
    int r = tid / NE;
    int idx = d_qoff[r] + edst[tid] - d_dlo[r];
    int pos = rowst[idx] + atomicAdd(&cur[idx], 1);
    elist[pos] = tid;
}

// ---- per-edge attention logits (no atomics) --------------------------------
__global__ __launch_bounds__(256) void edge_alpha(
    const float* __restrict__ Kb, const float* __restrict__ Qb,
    const int* __restrict__ esrc, const int* __restrict__ edst,
    const float* __restrict__ eattr, const float* __restrict__ We,
    float* __restrict__ alphab)
{
    int wid  = (blockIdx.x * blockDim.x + threadIdx.x) >> 6;
    int lane = threadIdx.x & 63;
    if (wid >= NEDGE) return;
    int r = wid / NE;
    int s = esrc[wid], d = edst[wid];
    float ea0 = eattr[2 * (long)wid], ea1 = eattr[2 * (long)wid + 1];
    float eemb = ea0 * We[r * 128 + lane] + ea1 * We[r * 128 + 64 + lane];
    float kv = Kb[((long)(d_koff[r] + s - d_slo[r])) * 64 + lane] + eemb;
    float qv = Qb[((long)(d_qoff[r] + d - d_dlo[r])) * 64 + lane];
    float p = qv * kv;
    #pragma unroll
    for (int m = 32; m > 0; m >>= 1) p += __shfl_xor(p, m);
    if (lane == 0) alphab[wid] = p * 0.125f;
}

// ---- per-node gather: softmax + weighted V sum, no atomics -----------------
template<int RELU>
__global__ __launch_bounds__(256) void gather(
    const float* __restrict__ Vb, const int* __restrict__ esrc,
    const float* __restrict__ eattr, const float* __restrict__ We,
    const float* __restrict__ alphab, const int* __restrict__ rowstart,
    const int* __restrict__ elist, const float* __restrict__ acc,
    float* __restrict__ outp)
{
    int n    = (blockIdx.x * blockDim.x + threadIdx.x) >> 6;
    int lane = threadIdx.x & 63;
    if (n >= NN) return;
    int t = n < 10000 ? 0 : n < 30000 ? 1 : n < 70000 ? 2 : 3;
    float a = acc[(long)n * 64 + lane];
    for (int ri = 0; ri < d_ntrel[t]; ++ri) {
        int r = d_trel[t][ri];
        int idx = d_qoff[r] + n - d_dlo[r];
        int e0 = rowstart[idx], e1 = rowstart[idx + 1];
        if (e0 == e1) continue;
        float m = -3.4e38f;
        for (int e = e0; e < e1; ++e) m = fmaxf(m, alphab[elist[e]]);
        float den = 0.f, vs = 0.f;
        float we0 = We[r * 128 + lane], we1 = We[r * 128 + 64 + lane];
        for (int e = e0; e < e1; ++e) {
            int eid = elist[e];
            float w = expf(alphab[eid] - m);
            den += w;
            int s = esrc[eid];
            float ea0 = eattr[2 * (long)eid], ea1 = eattr[2 * (long)eid + 1];
            float v = Vb[(long)(d_koff[r] + s - d_slo[r]) * 64 + lane]
                      + ea0 * we0 + ea1 * we1;
            vs = fmaf(w, v, vs);
        }
        a += vs / (den + 1e-16f);
    }
    outp[(long)n * 64 + lane] = RELU ? fmaxf(a, 0.f) : a;
}

// ---- head / power flow / final --------------------------------------------
__global__ __launch_bounds__(256) void head(
    const float* __restrict__ acc, const float* __restrict__ Wlin,
    float* __restrict__ out4)
{
    int wid  = (blockIdx.x * blockDim.x + threadIdx.x) >> 6;
    int lane = threadIdx.x & 63;
    if (wid >= NN) return;
    float hv = fmaxf(acc[(long)wid * 64 + lane], 0.f);
    float4 w = ((const float4*)Wlin)[lane];
    float p0 = hv * w.x, p1 = hv * w.y, p2 = hv * w.z, p3 = hv * w.w;
    #pragma unroll
    for (int m = 32; m > 0; m >>= 1) {
        p0 += __shfl_xor(p0, m);
        p1 += __shfl_xor(p1, m);
        p2 += __shfl_xor(p2, m);
        p3 += __shfl_xor(p3, m);
    }
    if (lane == 0) {
        out4[4 * (long)wid + 0] = p0;
        out4[4 * (long)wid + 1] = p1;
        out4[4 * (long)wid + 2] = p2;
        out4[4 * (long)wid + 3] = p3;
    }
}

__global__ __launch_bounds__(256) void pf_accum(
    const int* __restrict__ pfi, const int* __restrict__ pfj,
    const float* __restrict__ pfa, const float* __restrict__ out4,
    float* __restrict__ Pb, float* __restrict__ Qp)
{
    int e = blockIdx.x * blockDim.x + threadIdx.x;
    if (e >= EPF) return;
    int i = pfi[e], j = pfj[e];
    float r = pfa[2 * (long)e], x = pfa[2 * (long)e + 1];
    float dn = r * r + x * x;
    float G = r / dn, B = -x / dn;
    float thi = out4[4 * (long)i + 1], thj = out4[4 * (long)j + 1];
    float Vi = fabsf(out4[4 * (long)i]), Vj = fabsf(out4[4 * (long)j]);
    float dlt = thj - thi;
    float cd = cosf(dlt), sd = sinf(dlt);
    float vv = Vi * Vj;
    atomicAdd(&Pb[i], vv * (G * cd + B * sd));
    atomicAdd(&Qp[i], vv * (G * sd - B * cd));
}

__global__ __launch_bounds__(256) void final_out(
    const float* __restrict__ out4, const float* __restrict__ cons,
    const float* __restrict__ xin, const float* __restrict__ Pb,
    const float* __restrict__ Qp, float* __restrict__ out)
{
    int n = blockIdx.x * blockDim.x + threadIdx.x;
    if (n >= NN) return;
    const float* c = cons + 7 * (long)n;
    float th = out4[4 * (long)n + 1];
    float V  = fabsf(out4[4 * (long)n + 0]);
    float o0 = csig(V, c[0], c[1]) / xin[4 * (long)n + 0];
    float o2 = csig(Pb[n], c[3], c[4]);
    float o3 = csig(Qp[n], c[5], c[6]);
    out[4 * (long)n + 0] = o0;
    out[4 * (long)n + 1] = th;
    out[4 * (long)n + 2] = o2;
    out[4 * (long)n + 3] = o3;
}

extern "C" void kernel_launch(void* const* d_in, const int* in_sizes, int n_in,
                              void* d_out, int out_size, void* d_ws, size_t ws_size,
                              hipStream_t stream) {
    const float* xin  = (const float*)d_in[0];
    const float* cons = (const float*)d_in[1];
    const int*   esrc = (const int*)d_in[2];
    const int*   edst = (const int*)d_in[3];
    const float* eatt = (const float*)d_in[4];
    const int*   pfi  = (const int*)d_in[5];
    const int*   pfj  = (const int*)d_in[6];
    const float* pfa  = (const float*)d_in[7];

    const float* Wlin;
    int wb;
    if (in_sizes[8] == 256) { Wlin = (const float*)d_in[8];  wb = 9; }
    else                    { Wlin = (const float*)d_in[26]; wb = 8; }
    const float* Wq0 = (const float*)d_in[wb + 0];
    const float* bq0 = (const float*)d_in[wb + 1];
    const float* Wk0 = (const float*)d_in[wb + 2];
    const float* bk0 = (const float*)d_in[wb + 3];
    const float* Wv0 = (const float*)d_in[wb + 4];
    const float* bv0 = (const float*)d_in[wb + 5];
    const float* We0 = (const float*)d_in[wb + 6];
    const float* Ws0 = (const float*)d_in[wb + 7];
    const float* bs0 = (const float*)d_in[wb + 8];
    const float* Wq1 = (const float*)d_in[wb + 9];
    const float* bq1 = (const float*)d_in[wb + 10];
    const float* Wk1 = (const float*)d_in[wb + 11];
    const float* bk1 = (const float*)d_in[wb + 12];
    const float* Wv1 = (const float*)d_in[wb + 13];
    const float* bv1 = (const float*)d_in[wb + 14];
    const float* We1 = (const float*)d_in[wb + 15];
    const float* Ws1 = (const float*)d_in[wb + 16];
    const float* bs1 = (const float*)d_in[wb + 17];

    // ---- workspace layout (~255 MB total, fits proven >=342 MB bound) ----
    float* w = (float*)d_ws;
    size_t off = 0;
    float* h1     = w + off; off += (size_t)NN * 64;
    float* acc    = w + off; off += (size_t)NN * 64;
    float* KVb    = w + off; off += (size_t)NKV * 64;   // K during alpha, V during gather
    float* Qb     = w + off; off += (size_t)NQ * 64;
    float* alphab = w + off; off += (size_t)NEDGE;
    int*   rowst  = (int*)(w + off); off += NQ + 1;
    int*   cur    = (int*)(w + off); off += NQ;
    int*   bsum   = (int*)(w + off); off += 512;
    int*   elist  = (int*)(w + off); off += NEDGE;
    float* Wc0    = w + off; off += 4 * 4 * 64;
    float* Wc1    = w + off; off += 4 * 64 * 64;
    float* Pb     = w + off; off += NN;
    float* Qp     = w + off; off += NN;
    float* out4   = w + off; off += (size_t)NN * 4;
    if (ws_size < off * sizeof(float)) return;

    const int kqBlocks     = ((NKV / 16 + NQ / 16) + 3) / 4;
    const int vBlocks      = ((NKV / 16) + 3) / 4;
    const int skipBlocks   = ((NN / 16) + 3) / 4;
    const int edgeWaveBlks = (NEDGE + 3) / 4;
    const int nodeWaveBlks = (NN + 3) / 4;

    hipMemsetAsync(cur, 0, (size_t)NQ * 4, stream);
    hipMemsetAsync(Pb,  0, (size_t)NN * 4, stream);
    hipMemsetAsync(Qp,  0, (size_t)NN * 4, stream);

    // combined skip weights (both layers)
    combine_skip<4> <<<(4 * 4 * 64 + 255) / 256, 256, 0, stream>>>(Ws0, Wc0);
    combine_skip<64><<<(4 * 64 * 64 + 255) / 256, 256, 0, stream>>>(Ws1, Wc1);

    // CSR over (relation, dst) — static graph, reused by both layers
    csr_count<<<(NEDGE + 255) / 256, 256, 0, stream>>>(edst, cur);
    scan1<<<NB1, 1024, 0, stream>>>(cur, rowst, bsum);
    scan2<<<1, 512, 0, stream>>>(bsum);
    scan3<<<(NQ + 255) / 256, 256, 0, stream>>>(bsum, rowst);
    hipMemsetAsync(cur, 0, (size_t)NQ * 4, stream);
    csr_fill<<<(NEDGE + 255) / 256, 256, 0, stream>>>(edst, rowst, cur, elist);

    // ================= layer 0 (din=4, h = x) =================
    kq_mr<4><<<kqBlocks, 256, 0, stream>>>(xin, Wk0, bk0, Wq0, bq0, KVb, Qb);
    skip_mr<4><<<skipBlocks, 256, 0, stream>>>(xin, Wc0, bs0, acc);
    edge_alpha<<<edgeWaveBlks, 256, 0, stream>>>(KVb, Qb, esrc, edst, eatt, We0, alphab);
    v_mr<4><<<vBlocks, 256, 0, stream>>>(xin, Wv0, bv0, KVb);
    gather<1><<<nodeWaveBlks, 256, 0, stream>>>(KVb, esrc, eatt, We0, alphab, rowst, elist, acc, h1);

    // ================= layer 1 (din=64, h = h1) =================
    kq_mr<64><<<kqBlocks, 256, 0, stream>>>(h1, Wk1, bk1, Wq1, bq1, KVb, Qb);
    skip_mr<64><<<skipBlocks, 256, 0, stream>>>(h1, Wc1, bs1, acc);
    edge_alpha<<<edgeWaveBlks, 256, 0, stream>>>(KVb, Qb, esrc, edst, eatt, We1, alphab);
    v_mr<64><<<vBlocks, 256, 0, stream>>>(h1, Wv1, bv1, KVb);
    gather<0><<<nodeWaveBlks, 256, 0, stream>>>(KVb, esrc, eatt, We1, alphab, rowst, elist, acc, acc);

    // ================= head + power flow + final =================
    head<<<nodeWaveBlks, 256, 0, stream>>>(acc, Wlin, out4);
    pf_accum<<<(EPF + 255) / 256, 256, 0, stream>>>(pfi, pfj, pfa, out4, Pb, Qp);
    final_out<<<(NN + 255) / 256, 256, 0, stream>>>(out4, cons, xin, Pb, Qp, (float*)d_out);
}

// Round 9
// 1888.772 us; speedup vs baseline: 1.7193x; 1.2960x over previous
//
#include <hip/hip_runtime.h>
#include <hip/hip_bf16.h>

#define NREL 14
#define NE     100000
#define NEDGE  (NREL*NE)
#define NN     100000
#define EPF    800000
#define NQ     370000                 // sum of dst-range sizes over relations
#define NB1    ((NQ + 1023) / 1024)   // scan blocks = 362
#define QWAVES 5786                   // sum ceil(nd/64)
#define TWAVES 1564                   // sum ceil(typesize/64)

__device__ __constant__ int d_dlo[NREL]   = {10000,30000,70000,30000,70000,70000,0,0,0,10000,30000,10000,30000,70000};
__device__ __constant__ int d_qoff[NREL+1]= {0,20000,60000,90000,130000,160000,190000,200000,210000,220000,240000,280000,300000,340000,370000};
__device__ __constant__ int d_qwoff[NREL+1]={0,313,938,1407,2032,2501,2970,3127,3284,3441,3754,4379,4692,5317,5786};
__device__ __constant__ int d_trel[4][4]  = {{6,7,8,-1},{0,9,11,-1},{1,3,10,12},{2,4,5,13}};
__device__ __constant__ int d_ntrel[4]    = {3,3,4,4};
__device__ __constant__ int d_tbase[5]    = {0,10000,30000,70000,100000};
__device__ __constant__ int d_twoff[5]    = {0,157,470,1095,1564};

__device__ __forceinline__ float csig(float v, float lo, float hi) {
    float mid = 0.5f * (lo + hi);
    float s = 1.0f / (1.0f + expf(-0.1f * (v - mid)));
    return (s - 0.5f) * (hi - lo) + mid;
}

// ---- combined skip weights: Wc[t] = sum_{r: dst_type==t} Ws[r] -------------
template<int DIN>
__global__ __launch_bounds__(256) void combine_skip(
    const float* __restrict__ Ws, float* __restrict__ Wc)
{
    int tid = blockIdx.x * blockDim.x + threadIdx.x;
    if (tid >= 4 * DIN * 64) return;
    int t = tid / (DIN * 64), o = tid % (DIN * 64);
    float s = 0.f;
    for (int ri = 0; ri < d_ntrel[t]; ++ri) s += Ws[d_trel[t][ri] * DIN * 64 + o];
    Wc[tid] = s;
}

// ---- relation prep: M2T[r][j][i] = sum_c Wk[r][i][c]*Wq[r][j][c] ----------
template<int DIN>
__global__ __launch_bounds__(256) void mk_m2t(
    const float* __restrict__ Wk, const float* __restrict__ Wq,
    float* __restrict__ M2T)
{
    int tid = blockIdx.x * blockDim.x + threadIdx.x;
    if (tid >= NREL * DIN * DIN) return;
    int r = tid / (DIN * DIN), rem = tid % (DIN * DIN);
    int i = rem / DIN, j = rem % DIN;
    const float* wki = Wk + (long)r * DIN * 64 + i * 64;
    const float* wqj = Wq + (long)r * DIN * 64 + j * 64;
    float s = 0.f;
    for (int c = 0; c < 64; ++c) s = fmaf(wki[c], wqj[c], s);
    M2T[(long)r * DIN * DIN + j * DIN + i] = s;
}

// vec4[r][k][i]: k=0: Wk bq (u init); k=1: Wq we0; k=2: Wq we1; k=3: Wq bk
template<int DIN>
__global__ __launch_bounds__(256) void mk_vecs(
    const float* __restrict__ Wk, const float* __restrict__ Wq,
    const float* __restrict__ bq, const float* __restrict__ bk,
    const float* __restrict__ We, float* __restrict__ vec4)
{
    int tid = blockIdx.x * blockDim.x + threadIdx.x;
    if (tid >= NREL * 4 * DIN) return;
    int r = tid / (4 * DIN), rem = tid % (4 * DIN);
    int k = rem / DIN, i = rem % DIN;
    const float* row; const float* v;
    if (k == 0) { row = Wk + (long)r * DIN * 64 + i * 64; v = bq + r * 64; }
    else {
        row = Wq + (long)r * DIN * 64 + i * 64;
        v = (k == 1) ? We + r * 128 : (k == 2) ? We + r * 128 + 64 : bk + r * 64;
    }
    float s = 0.f;
    for (int c = 0; c < 64; ++c) s = fmaf(row[c], v[c], s);
    vec4[tid] = s;
}

// scl[r] = (bq.we0, bq.we1, bk.bq, 0)
__global__ __launch_bounds__(64) void mk_scl(
    const float* __restrict__ bq, const float* __restrict__ bk,
    const float* __restrict__ We, float* __restrict__ scl)
{
    int r = blockIdx.x * blockDim.x + threadIdx.x;
    if (r >= NREL) return;
    float s0 = 0.f, s1 = 0.f, sb = 0.f;
    for (int c = 0; c < 64; ++c) {
        float b = bq[r * 64 + c];
        s0 = fmaf(b, We[r * 128 + c], s0);
        s1 = fmaf(b, We[r * 128 + 64 + c], s1);
        sb = fmaf(b, bk[r * 64 + c], sb);
    }
    scl[4 * r] = s0; scl[4 * r + 1] = s1; scl[4 * r + 2] = sb; scl[4 * r + 3] = 0.f;
}

// ---- per-dst prep: u = M2 h_d + Wk bq ; scal = (c0,c1,cb,0) ---------------
// lane = dst row; weights/M2T wave-uniform (scalar-cached)
template<int DIN>
__global__ __launch_bounds__(256) void dstprep(
    const float* __restrict__ h, const float* __restrict__ M2T,
    const float* __restrict__ vec4, const float* __restrict__ scl,
    float* __restrict__ ug, float* __restrict__ scal)
{
    int wv   = (blockIdx.x * blockDim.x + threadIdx.x) >> 6;
    int lane = threadIdx.x & 63;
    if (wv >= QWAVES) return;
    int r = 0;
    while (r < NREL - 1 && wv >= d_qwoff[r + 1]) ++r;
    int local = (wv - d_qwoff[r]) * 64 + lane;
    int nd = d_qoff[r + 1] - d_qoff[r];
    bool act = local < nd;
    int lcl = act ? local : nd - 1;
    int node = d_dlo[r] + lcl;
    long hb = (long)node * DIN;
    const float* m2 = M2T + (long)r * DIN * DIN;
    const float* vb = vec4 + (long)r * 4 * DIN;
    float acc[DIN];
    #pragma unroll
    for (int c = 0; c < DIN; ++c) acc[c] = vb[c];          // Wk bq
    float sc0 = scl[4 * r], sc1 = scl[4 * r + 1], scb = scl[4 * r + 2];
    for (int j = 0; j < DIN; ++j) {
        float hv = h[hb + j];
        const float* mj = m2 + j * DIN;
        #pragma unroll
        for (int c = 0; c < DIN; ++c) acc[c] = fmaf(hv, mj[c], acc[c]);
        sc0 = fmaf(hv, vb[DIN + j],     sc0);
        sc1 = fmaf(hv, vb[2 * DIN + j], sc1);
        scb = fmaf(hv, vb[3 * DIN + j], scb);
    }
    if (act) {
        long idx = d_qoff[r] + lcl;
        float4* o = (float4*)(ug + idx * DIN);
        #pragma unroll
        for (int c = 0; c < DIN / 4; ++c)
            o[c] = make_float4(acc[4*c], acc[4*c+1], acc[4*c+2], acc[4*c+3]);
        ((float4*)scal)[idx] = make_float4(sc0, sc1, scb, 0.f);
    }
}

// ---- CSR build (static graph) ---------------------------------------------
__global__ __launch_bounds__(256) void csr_count(
    const int* __restrict__ edst, int* __restrict__ cur)
{
    int tid = blockIdx.x * blockDim.x + threadIdx.x;
    if (tid >= NEDGE) return;
    int r = tid / NE;
    atomicAdd(&cur[d_qoff[r] + edst[tid] - d_dlo[r]], 1);
}

__global__ __launch_bounds__(1024) void scan1(
    const int* __restrict__ cur, int* __restrict__ rowst, int* __restrict__ bsum)
{
    __shared__ int s[1024];
    int t = threadIdx.x, g = blockIdx.x * 1024 + t;
    s[t] = g < NQ ? cur[g] : 0;
    __syncthreads();
    for (int o = 1; o < 1024; o <<= 1) {
        int x = t >= o ? s[t - o] : 0;
        __syncthreads();
        s[t] += x;
        __syncthreads();
    }
    if (g < NQ) rowst[g + 1] = s[t];
    if (t == 1023) bsum[blockIdx.x] = s[1023];
}

__global__ __launch_bounds__(512) void scan2(int* __restrict__ bsum)
{
    __shared__ int s[512];
    int t = threadIdx.x;
    s[t] = t < NB1 ? bsum[t] : 0;
    __syncthreads();
    for (int o = 1; o < 512; o <<= 1) {
        int x = t >= o ? s[t - o] : 0;
        __syncthreads();
        s[t] += x;
        __syncthreads();
    }
    if (t < NB1) bsum[t] = (t == 0) ? 0 : s[t - 1];
}

__global__ __launch_bounds__(256) void scan3(
    const int* __restrict__ bsum, int* __restrict__ rowst)
{
    int g = blockIdx.x * blockDim.x + threadIdx.x;
    if (g == 0) rowst[0] = 0;
    if (g < NQ) rowst[g + 1] += bsum[g >> 10];
}

__global__ __launch_bounds__(256) void csr_fill(
    const int* __restrict__ edst, const int* __restrict__ rowst,
    int* __restrict__ cur, int* __restrict__ elist)
{
    int tid = blockIdx.x * blockDim.x + threadIdx.x;
    if (tid >= NEDGE) return;
    int r = tid / NE;
    int idx = d_qoff[r] + edst[tid] - d_dlo[r];
    int pos = rowst[idx] + atomicAdd(&cur[idx], 1);
    elist[pos] = tid;
}

// ---- edge alpha: alpha = 0.125*(h_s.u_d + cb + ea0 c0 + ea1 c1) -----------
__global__ __launch_bounds__(256) void edge_alpha_t4(          // din=4: thread/edge
    const float* __restrict__ h, const float* __restrict__ ug,
    const float* __restrict__ scal,
    const int* __restrict__ esrc, const int* __restrict__ edst,
    const float* __restrict__ eattr, float* __restrict__ alphab)
{
    int e = blockIdx.x * blockDim.x + threadIdx.x;
    if (e >= NEDGE) return;
    int r = e / NE;
    long idx = d_qoff[r] + edst[e] - d_dlo[r];
    float4 hs = ((const float4*)h)[esrc[e]];
    float4 ud = ((const float4*)ug)[idx];
    float4 sc = ((const float4*)scal)[idx];
    float ea0 = eattr[2 * (long)e], ea1 = eattr[2 * (long)e + 1];
    float p = hs.x*ud.x + hs.y*ud.y + hs.z*ud.z + hs.w*ud.w
            + sc.z + ea0 * sc.x + ea1 * sc.y;
    alphab[e] = 0.125f * p;
}

__global__ __launch_bounds__(256) void edge_alpha_w(           // din=64: wave/edge
    const float* __restrict__ h, const float* __restrict__ ug,
    const float* __restrict__ scal,
    const int* __restrict__ esrc, const int* __restrict__ edst,
    const float* __restrict__ eattr, float* __restrict__ alphab)
{
    int e    = (blockIdx.x * blockDim.x + threadIdx.x) >> 6;
    int lane = threadIdx.x & 63;
    if (e >= NEDGE) return;
    int r = e / NE;
    long idx = d_qoff[r] + edst[e] - d_dlo[r];
    float p = h[(long)esrc[e] * 64 + lane] * ug[idx * 64 + lane];
    #pragma unroll
    for (int m = 32; m > 0; m >>= 1) p += __shfl_xor(p, m);
    if (lane == 0) {
        float4 sc = ((const float4*)scal)[idx];
        float ea0 = eattr[2 * (long)e], ea1 = eattr[2 * (long)e + 1];
        alphab[e] = 0.125f * (p + sc.z + ea0 * sc.x + ea1 * sc.y);
    }
}

// ---- gather: g_d = sum_e w_e h_s ; m_d = sum_e w_e ea  (normalized) -------
__global__ __launch_bounds__(256) void gather_t4(              // din=4: thread/idx
    const float* __restrict__ h, const int* __restrict__ esrc,
    const float* __restrict__ eattr, const float* __restrict__ alphab,
    const int* __restrict__ rowst, const int* __restrict__ elist,
    float* __restrict__ ug, float* __restrict__ gm)
{
    int idx = blockIdx.x * blockDim.x + threadIdx.x;
    if (idx >= NQ) return;
    int e0 = rowst[idx], e1 = rowst[idx + 1];
    if (e0 == e1) {
        ((float4*)ug)[idx] = make_float4(0.f,0.f,0.f,0.f);
        gm[2 * (long)idx] = 0.f; gm[2 * (long)idx + 1] = 0.f;
        return;
    }
    float m = -3.4e38f;
    for (int e = e0; e < e1; ++e) m = fmaxf(m, alphab[elist[e]]);
    float den = 0.f, m0 = 0.f, m1 = 0.f;
    float gx = 0.f, gy = 0.f, gz = 0.f, gw = 0.f;
    for (int e = e0; e < e1; ++e) {
        int eid = elist[e];
        float a = expf(alphab[eid] - m);
        den += a;
        float4 hs = ((const float4*)h)[esrc[eid]];
        gx = fmaf(a, hs.x, gx); gy = fmaf(a, hs.y, gy);
        gz = fmaf(a, hs.z, gz); gw = fmaf(a, hs.w, gw);
        m0 = fmaf(a, eattr[2 * (long)eid],     m0);
        m1 = fmaf(a, eattr[2 * (long)eid + 1], m1);
    }
    float inv = 1.f / (den + 1e-16f);
    ((float4*)ug)[idx] = make_float4(gx*inv, gy*inv, gz*inv, gw*inv);
    gm[2 * (long)idx] = m0 * inv; gm[2 * (long)idx + 1] = m1 * inv;
}

__global__ __launch_bounds__(256) void gather_w(               // din=64: wave/idx
    const float* __restrict__ h, const int* __restrict__ esrc,
    const float* __restrict__ eattr, const float* __restrict__ alphab,
    const int* __restrict__ rowst, const int* __restrict__ elist,
    float* __restrict__ ug, float* __restrict__ gm)
{
    int idx  = (blockIdx.x * blockDim.x + threadIdx.x) >> 6;
    int lane = threadIdx.x & 63;
    if (idx >= NQ) return;
    int e0 = rowst[idx], e1 = rowst[idx + 1];
    if (e0 == e1) {
        ug[(long)idx * 64 + lane] = 0.f;
        if (lane == 0) { gm[2*(long)idx] = 0.f; gm[2*(long)idx+1] = 0.f; }
        return;
    }
    float m = -3.4e38f;
    for (int e = e0; e < e1; ++e) m = fmaxf(m, alphab[elist[e]]);
    float den = 0.f, m0 = 0.f, m1 = 0.f, g = 0.f;
    for (int e = e0; e < e1; ++e) {
        int eid = elist[e];
        float a = expf(alphab[eid] - m);
        den += a;
        g  = fmaf(a, h[(long)esrc[eid] * 64 + lane], g);
        m0 = fmaf(a, eattr[2 * (long)eid],     m0);
        m1 = fmaf(a, eattr[2 * (long)eid + 1], m1);
    }
    float inv = 1.f / (den + 1e-16f);
    ug[(long)idx * 64 + lane] = g * inv;
    if (lane == 0) { gm[2*(long)idx] = m0 * inv; gm[2*(long)idx+1] = m1 * inv; }
}

// ---- combine: out[n] = skip + sum_r [ g@Wv + hasE*bv + m@We ] -------------
// lane = node; wave = 64 nodes of one type
template<int DIN, int RELU>
__global__ __launch_bounds__(256) void combine(
    const float* __restrict__ h, const float* __restrict__ Wc,
    const float* __restrict__ bs, const float* __restrict__ Wv,
    const float* __restrict__ bv, const float* __restrict__ We,
    const float* __restrict__ ug, const float* __restrict__ gm,
    const int* __restrict__ rowst, float* __restrict__ outp)
{
    int wv   = (blockIdx.x * blockDim.x + threadIdx.x) >> 6;
    int lane = threadIdx.x & 63;
    if (wv >= TWAVES) return;
    int t = 0;
    while (t < 3 && wv >= d_twoff[t + 1]) ++t;
    int nl = d_tbase[t] + (wv - d_twoff[t]) * 64 + lane;
    bool act = nl < d_tbase[t + 1];
    int node = act ? nl : d_tbase[t + 1] - 1;
    float a[64];
    #pragma unroll
    for (int c = 0; c < 64; ++c) a[c] = 0.f;
    // skip: h @ Wc[t]  (+ sum bs)
    {
        long hb = (long)node * DIN;
        const float* wp = Wc + (long)t * DIN * 64;
        for (int j = 0; j < DIN; ++j) {
            float hv = h[hb + j];
            const float* wj = wp + j * 64;
            #pragma unroll
            for (int c = 0; c < 64; ++c) a[c] = fmaf(hv, wj[c], a[c]);
        }
    }
    int nr = d_ntrel[t];
    for (int ri = 0; ri < nr; ++ri) {
        int r = d_trel[t][ri];
        long idx = d_qoff[r] + node - d_dlo[r];
        float he = (rowst[idx + 1] > rowst[idx]) ? 1.f : 0.f;
        const float* wvp = Wv + (long)r * DIN * 64;
        long gb = idx * DIN;
        for (int j = 0; j < DIN; ++j) {
            float gv = ug[gb + j];
            const float* wj = wvp + j * 64;
            #pragma unroll
            for (int c = 0; c < 64; ++c) a[c] = fmaf(gv, wj[c], a[c]);
        }
        float g0 = gm[2 * idx], g1 = gm[2 * idx + 1];
        const float* bsr = bs + r * 64;
        const float* bvr = bv + r * 64;
        const float* we0 = We + r * 128;
        const float* we1 = We + r * 128 + 64;
        #pragma unroll
        for (int c = 0; c < 64; ++c)
            a[c] += bsr[c] + he * bvr[c] + g0 * we0[c] + g1 * we1[c];
    }
    if (act) {
        float4* o = (float4*)(outp + (long)node * 64);
        #pragma unroll
        for (int c = 0; c < 16; ++c) {
            float x0 = a[4*c], x1 = a[4*c+1], x2 = a[4*c+2], x3 = a[4*c+3];
            if (RELU) { x0=fmaxf(x0,0.f); x1=fmaxf(x1,0.f); x2=fmaxf(x2,0.f); x3=fmaxf(x3,0.f); }
            o[c] = make_float4(x0, x1, x2, x3);
        }
    }
}

// ---- head / power flow / final --------------------------------------------
__global__ __launch_bounds__(256) void head(
    const float* __restrict__ acc, const float* __restrict__ Wlin,
    float* __restrict__ out4)
{
    int wid  = (blockIdx.x * blockDim.x + threadIdx.x) >> 6;
    int lane = threadIdx.x & 63;
    if (wid >= NN) return;
    float hv = fmaxf(acc[(long)wid * 64 + lane], 0.f);
    float4 w = ((const float4*)Wlin)[lane];
    float p0 = hv * w.x, p1 = hv * w.y, p2 = hv * w.z, p3 = hv * w.w;
    #pragma unroll
    for (int m = 32; m > 0; m >>= 1) {
        p0 += __shfl_xor(p0, m);
        p1 += __shfl_xor(p1, m);
        p2 += __shfl_xor(p2, m);
        p3 += __shfl_xor(p3, m);
    }
    if (lane == 0) {
        out4[4 * (long)wid + 0] = p0;
        out4[4 * (long)wid + 1] = p1;
        out4[4 * (long)wid + 2] = p2;
        out4[4 * (long)wid + 3] = p3;
    }
}

__global__ __launch_bounds__(256) void pf_accum(
    const int* __restrict__ pfi, const int* __restrict__ pfj,
    const float* __restrict__ pfa, const float* __restrict__ out4,
    float* __restrict__ Pb, float* __restrict__ Qp)
{
    int e = blockIdx.x * blockDim.x + threadIdx.x;
    if (e >= EPF) return;
    int i = pfi[e], j = pfj[e];
    float r = pfa[2 * (long)e], x = pfa[2 * (long)e + 1];
    float dn = r * r + x * x;
    float G = r / dn, B = -x / dn;
    float thi = out4[4 * (long)i + 1], thj = out4[4 * (long)j + 1];
    float Vi = fabsf(out4[4 * (long)i]), Vj = fabsf(out4[4 * (long)j]);
    float dlt = thj - thi;
    float cd = cosf(dlt), sd = sinf(dlt);
    float vv = Vi * Vj;
    atomicAdd(&Pb[i], vv * (G * cd + B * sd));
    atomicAdd(&Qp[i], vv * (G * sd - B * cd));
}

__global__ __launch_bounds__(256) void final_out(
    const float* __restrict__ out4, const float* __restrict__ cons,
    const float* __restrict__ xin, const float* __restrict__ Pb,
    const float* __restrict__ Qp, float* __restrict__ out)
{
    int n = blockIdx.x * blockDim.x + threadIdx.x;
    if (n >= NN) return;
    const float* c = cons + 7 * (long)n;
    float th = out4[4 * (long)n + 1];
    float V  = fabsf(out4[4 * (long)n + 0]);
    float o0 = csig(V, c[0], c[1]) / xin[4 * (long)n + 0];
    float o2 = csig(Pb[n], c[3], c[4]);
    float o3 = csig(Qp[n], c[5], c[6]);
    out[4 * (long)n + 0] = o0;
    out[4 * (long)n + 1] = th;
    out[4 * (long)n + 2] = o2;
    out[4 * (long)n + 3] = o3;
}

extern "C" void kernel_launch(void* const* d_in, const int* in_sizes, int n_in,
                              void* d_out, int out_size, void* d_ws, size_t ws_size,
                              hipStream_t stream) {
    const float* xin  = (const float*)d_in[0];
    const float* cons = (const float*)d_in[1];
    const int*   esrc = (const int*)d_in[2];
    const int*   edst = (const int*)d_in[3];
    const float* eatt = (const float*)d_in[4];
    const int*   pfi  = (const int*)d_in[5];
    const int*   pfj  = (const int*)d_in[6];
    const float* pfa  = (const float*)d_in[7];

    const float* Wlin;
    int wb;
    if (in_sizes[8] == 256) { Wlin = (const float*)d_in[8];  wb = 9; }
    else                    { Wlin = (const float*)d_in[26]; wb = 8; }
    const float* Wq0 = (const float*)d_in[wb + 0];
    const float* bq0 = (const float*)d_in[wb + 1];
    const float* Wk0 = (const float*)d_in[wb + 2];
    const float* bk0 = (const float*)d_in[wb + 3];
    const float* Wv0 = (const float*)d_in[wb + 4];
    const float* bv0 = (const float*)d_in[wb + 5];
    const float* We0 = (const float*)d_in[wb + 6];
    const float* Ws0 = (const float*)d_in[wb + 7];
    const float* bs0 = (const float*)d_in[wb + 8];
    const float* Wq1 = (const float*)d_in[wb + 9];
    const float* bq1 = (const float*)d_in[wb + 10];
    const float* Wk1 = (const float*)d_in[wb + 11];
    const float* bk1 = (const float*)d_in[wb + 12];
    const float* Wv1 = (const float*)d_in[wb + 13];
    const float* bv1 = (const float*)d_in[wb + 14];
    const float* We1 = (const float*)d_in[wb + 15];
    const float* Ws1 = (const float*)d_in[wb + 16];
    const float* bs1 = (const float*)d_in[wb + 17];

    // ---- workspace layout (~170 MB) ----
    float* w = (float*)d_ws;
    size_t off = 0;
    float* h1     = w + off; off += (size_t)NN * 64;        // 25.6 MB
    float* acc    = w + off; off += (size_t)NN * 64;        // 25.6 MB
    float* ug     = w + off; off += (size_t)NQ * 64;        // 94.7 MB (u then g)
    float* scal   = w + off; off += (size_t)NQ * 4;         //  5.9 MB
    float* gm     = w + off; off += (size_t)NQ * 2;         //  3.0 MB
    float* alphab = w + off; off += (size_t)NEDGE;          //  5.6 MB
    int*   rowst  = (int*)(w + off); off += NQ + 1;
    int*   cur    = (int*)(w + off); off += NQ;
    int*   bsum   = (int*)(w + off); off += 512;
    int*   elist  = (int*)(w + off); off += NEDGE;          //  5.6 MB
    float* M2T    = w + off; off += (size_t)NREL * 64 * 64; //  0.23 MB (L0 uses 16/rel)
    float* vec4   = w + off; off += (size_t)NREL * 4 * 64;
    float* sclr   = w + off; off += NREL * 4;
    float* Wc0    = w + off; off += 4 * 4 * 64;
    float* Wc1    = w + off; off += 4 * 64 * 64;
    float* Pb     = w + off; off += NN;
    float* Qp     = w + off; off += NN;
    float* out4   = w + off; off += (size_t)NN * 4;
    if (ws_size < off * sizeof(float)) return;

    const int dpBlocks   = (QWAVES + 3) / 4;     // 1447
    const int cbBlocks   = (TWAVES + 3) / 4;     // 391
    const int eaWBlocks  = (NEDGE + 3) / 4;      // wave/edge
    const int gaWBlocks  = (NQ + 3) / 4;         // wave/idx
    const int nodeWaveBlks = (NN + 3) / 4;

    hipMemsetAsync(cur, 0, (size_t)NQ * 4, stream);
    hipMemsetAsync(Pb,  0, (size_t)NN * 4, stream);
    hipMemsetAsync(Qp,  0, (size_t)NN * 4, stream);

    combine_skip<4> <<<(4*4*64 + 255)/256, 256, 0, stream>>>(Ws0, Wc0);
    combine_skip<64><<<(4*64*64 + 255)/256, 256, 0, stream>>>(Ws1, Wc1);

    // CSR (static graph, shared by both layers)
    csr_count<<<(NEDGE + 255)/256, 256, 0, stream>>>(edst, cur);
    scan1<<<NB1, 1024, 0, stream>>>(cur, rowst, bsum);
    scan2<<<1, 512, 0, stream>>>(bsum);
    scan3<<<(NQ + 255)/256, 256, 0, stream>>>(bsum, rowst);
    hipMemsetAsync(cur, 0, (size_t)NQ * 4, stream);
    csr_fill<<<(NEDGE + 255)/256, 256, 0, stream>>>(edst, rowst, cur, elist);

    // ================= layer 0 (din=4, h = x) =================
    mk_m2t<4><<<(NREL*16 + 255)/256, 256, 0, stream>>>(Wk0, Wq0, M2T);
    mk_vecs<4><<<(NREL*16 + 255)/256, 256, 0, stream>>>(Wk0, Wq0, bq0, bk0, We0, vec4);
    mk_scl<<<1, 64, 0, stream>>>(bq0, bk0, We0, sclr);
    dstprep<4><<<dpBlocks, 256, 0, stream>>>(xin, M2T, vec4, sclr, ug, scal);
    edge_alpha_t4<<<(NEDGE + 255)/256, 256, 0, stream>>>(xin, ug, scal, esrc, edst, eatt, alphab);
    gather_t4<<<(NQ + 255)/256, 256, 0, stream>>>(xin, esrc, eatt, alphab, rowst, elist, ug, gm);
    combine<4,1><<<cbBlocks, 256, 0, stream>>>(xin, Wc0, bs0, Wv0, bv0, We0, ug, gm, rowst, h1);

    // ================= layer 1 (din=64, h = h1) =================
    mk_m2t<64><<<(NREL*64*64 + 255)/256, 256, 0, stream>>>(Wk1, Wq1, M2T);
    mk_vecs<64><<<(NREL*4*64 + 255)/256, 256, 0, stream>>>(Wk1, Wq1, bq1, bk1, We1, vec4);
    mk_scl<<<1, 64, 0, stream>>>(bq1, bk1, We1, sclr);
    dstprep<64><<<dpBlocks, 256, 0, stream>>>(h1, M2T, vec4, sclr, ug, scal);
    edge_alpha_w<<<eaWBlocks, 256, 0, stream>>>(h1, ug, scal, esrc, edst, eatt, alphab);
    gather_w<<<gaWBlocks, 256, 0, stream>>>(h1, esrc, eatt, alphab, rowst, elist, ug, gm);
    combine<64,0><<<cbBlocks, 256, 0, stream>>>(h1, Wc1, bs1, Wv1, bv1, We1, ug, gm, rowst, acc);

    // ================= head + power flow + final =================
    head<<<nodeWaveBlks, 256, 0, stream>>>(acc, Wlin, out4);
    pf_accum<<<(EPF + 255)/256, 256, 0, stream>>>(pfi, pfj, pfa, out4, Pb, Qp);
    final_out<<<(NN + 255)/256, 256, 0, stream>>>(out4, cons, xin, Pb, Qp, (float*)d_out);
}

// Round 10
// 1320.649 us; speedup vs baseline: 2.4590x; 1.4302x over previous
//
#include <hip/hip_runtime.h>
#include <hip/hip_bf16.h>

#define NREL 14
#define NE     100000
#define NEDGE  (NREL*NE)
#define NN     100000
#define EPF    800000
#define NQ     370000                 // sum of dst-range sizes over relations
#define NB1    ((NQ + 1023) / 1024)   // scan blocks = 362
#define QWAVES 5786                   // sum ceil(nd/64) (also GEMM blocks)
#define TWAVES 1564                   // sum ceil(typesize/64)

__device__ __constant__ int d_dlo[NREL]   = {10000,30000,70000,30000,70000,70000,0,0,0,10000,30000,10000,30000,70000};
__device__ __constant__ int d_qoff[NREL+1]= {0,20000,60000,90000,130000,160000,190000,200000,210000,220000,240000,280000,300000,340000,370000};
__device__ __constant__ int d_qwoff[NREL+1]={0,313,938,1407,2032,2501,2970,3127,3284,3441,3754,4379,4692,5317,5786};
__device__ __constant__ int d_trel[4][4]  = {{6,7,8,-1},{0,9,11,-1},{1,3,10,12},{2,4,5,13}};
__device__ __constant__ int d_ntrel[4]    = {3,3,4,4};
__device__ __constant__ int d_tbase[5]    = {0,10000,30000,70000,100000};
__device__ __constant__ int d_twoff[5]    = {0,157,470,1095,1564};

__device__ __forceinline__ float csig(float v, float lo, float hi) {
    float mid = 0.5f * (lo + hi);
    float s = 1.0f / (1.0f + expf(-0.1f * (v - mid)));
    return (s - 0.5f) * (hi - lo) + mid;
}

// ==================== tiled-GEMM building blocks ===========================
// stage input tile transposed: sIn[k][row] <- src[(l0+row) clamped][k]
template<int K>
__device__ __forceinline__ void stage_in(
    float* sIn, const float* __restrict__ src, int l0, int n, int tid)
{
    if (K == 4) {
        if (tid < 64) {
            int lcl = min(l0 + tid, n - 1);
            float4 v = *(const float4*)(src + (long)lcl * 4);
            sIn[0 * 64 + tid] = v.x; sIn[1 * 64 + tid] = v.y;
            sIn[2 * 64 + tid] = v.z; sIn[3 * 64 + tid] = v.w;
        }
    } else {
        int row = tid >> 2, q = tid & 3;
        int lcl = min(l0 + row, n - 1);
        const float* p = src + (long)lcl * 64 + q * 16;
        #pragma unroll
        for (int kk = 0; kk < 4; ++kk) {
            float4 v = *(const float4*)(p + kk * 4);
            int k = q * 16 + kk * 4;
            sIn[(k + 0) * 64 + row] = v.x;
            sIn[(k + 1) * 64 + row] = v.y;
            sIn[(k + 2) * 64 + row] = v.z;
            sIn[(k + 3) * 64 + row] = v.w;
        }
    }
}

// stage weight tile: sW[k][c] <- src[k][c]  (row-major K x 64)
template<int K>
__device__ __forceinline__ void stage_w(
    float* sW, const float* __restrict__ src, int tid)
{
    for (int i = tid * 4; i < K * 64; i += 1024)
        *(float4*)(sW + i) = *(const float4*)(src + i);
}

template<int K>
__device__ __forceinline__ void mma_t(
    float acc[4][4], const float* sIn, const float* sW, int r0, int c0)
{
    for (int k = 0; k < K; ++k) {
        float4 a = *(const float4*)(sIn + k * 64 + r0);
        float4 b = *(const float4*)(sW + k * 64 + c0);
        acc[0][0] = fmaf(a.x, b.x, acc[0][0]);
        acc[0][1] = fmaf(a.x, b.y, acc[0][1]);
        acc[0][2] = fmaf(a.x, b.z, acc[0][2]);
        acc[0][3] = fmaf(a.x, b.w, acc[0][3]);
        acc[1][0] = fmaf(a.y, b.x, acc[1][0]);
        acc[1][1] = fmaf(a.y, b.y, acc[1][1]);
        acc[1][2] = fmaf(a.y, b.z, acc[1][2]);
        acc[1][3] = fmaf(a.y, b.w, acc[1][3]);
        acc[2][0] = fmaf(a.z, b.x, acc[2][0]);
        acc[2][1] = fmaf(a.z, b.y, acc[2][1]);
        acc[2][2] = fmaf(a.z, b.z, acc[2][2]);
        acc[2][3] = fmaf(a.z, b.w, acc[2][3]);
        acc[3][0] = fmaf(a.w, b.x, acc[3][0]);
        acc[3][1] = fmaf(a.w, b.y, acc[3][1]);
        acc[3][2] = fmaf(a.w, b.z, acc[3][2]);
        acc[3][3] = fmaf(a.w, b.w, acc[3][3]);
    }
}

// ---- combined skip weights: Wc[t] = sum_{r: dst_type==t} Ws[r] -------------
template<int DIN>
__global__ __launch_bounds__(256) void combine_skip(
    const float* __restrict__ Ws, float* __restrict__ Wc)
{
    int tid = blockIdx.x * blockDim.x + threadIdx.x;
    if (tid >= 4 * DIN * 64) return;
    int t = tid / (DIN * 64), o = tid % (DIN * 64);
    float s = 0.f;
    for (int ri = 0; ri < d_ntrel[t]; ++ri) s += Ws[d_trel[t][ri] * DIN * 64 + o];
    Wc[tid] = s;
}

// ---- relation prep: M2T[r][j][i] = sum_c Wk[r][i][c]*Wq[r][j][c] ----------
template<int DIN>
__global__ __launch_bounds__(256) void mk_m2t(
    const float* __restrict__ Wk, const float* __restrict__ Wq,
    float* __restrict__ M2T)
{
    int tid = blockIdx.x * blockDim.x + threadIdx.x;
    if (tid >= NREL * DIN * DIN) return;
    int r = tid / (DIN * DIN), rem = tid % (DIN * DIN);
    int i = rem / DIN, j = rem % DIN;
    const float* wki = Wk + (long)r * DIN * 64 + i * 64;
    const float* wqj = Wq + (long)r * DIN * 64 + j * 64;
    float s = 0.f;
    for (int c = 0; c < 64; ++c) s = fmaf(wki[c], wqj[c], s);
    M2T[(long)r * DIN * DIN + j * DIN + i] = s;
}

// vec4[r][k][i]: k=0: Wk bq (u init); k=1: Wq we0; k=2: Wq we1; k=3: Wq bk
template<int DIN>
__global__ __launch_bounds__(256) void mk_vecs(
    const float* __restrict__ Wk, const float* __restrict__ Wq,
    const float* __restrict__ bq, const float* __restrict__ bk,
    const float* __restrict__ We, float* __restrict__ vec4)
{
    int tid = blockIdx.x * blockDim.x + threadIdx.x;
    if (tid >= NREL * 4 * DIN) return;
    int r = tid / (4 * DIN), rem = tid % (4 * DIN);
    int k = rem / DIN, i = rem % DIN;
    const float* row; const float* v;
    if (k == 0) { row = Wk + (long)r * DIN * 64 + i * 64; v = bq + r * 64; }
    else {
        row = Wq + (long)r * DIN * 64 + i * 64;
        v = (k == 1) ? We + r * 128 : (k == 2) ? We + r * 128 + 64 : bk + r * 64;
    }
    float s = 0.f;
    for (int c = 0; c < 64; ++c) s = fmaf(row[c], v[c], s);
    vec4[tid] = s;
}

// scl[r] = (bq.we0, bq.we1, bk.bq, 0)
__global__ __launch_bounds__(64) void mk_scl(
    const float* __restrict__ bq, const float* __restrict__ bk,
    const float* __restrict__ We, float* __restrict__ scl)
{
    int r = blockIdx.x * blockDim.x + threadIdx.x;
    if (r >= NREL) return;
    float s0 = 0.f, s1 = 0.f, sb = 0.f;
    for (int c = 0; c < 64; ++c) {
        float b = bq[r * 64 + c];
        s0 = fmaf(b, We[r * 128 + c], s0);
        s1 = fmaf(b, We[r * 128 + 64 + c], s1);
        sb = fmaf(b, bk[r * 64 + c], sb);
    }
    scl[4 * r] = s0; scl[4 * r + 1] = s1; scl[4 * r + 2] = sb; scl[4 * r + 3] = 0.f;
}

// ---- layer0 per-dst prep (din=4, tiny): u float4 + scal -------------------
__global__ __launch_bounds__(256) void dstprep4(
    const float* __restrict__ h, const float* __restrict__ M2T,
    const float* __restrict__ vec4, const float* __restrict__ scl,
    float* __restrict__ ug, float* __restrict__ scal)
{
    int idx = blockIdx.x * blockDim.x + threadIdx.x;
    if (idx >= NQ) return;
    int r = 0;
    while (r < NREL - 1 && idx >= d_qoff[r + 1]) ++r;
    int node = d_dlo[r] + (idx - d_qoff[r]);
    float4 hv = ((const float4*)h)[node];
    const float* m2 = M2T + (long)r * 16;
    const float* vb = vec4 + (long)r * 16;
    float u[4];
    #pragma unroll
    for (int c = 0; c < 4; ++c)
        u[c] = vb[c] + hv.x * m2[c] + hv.y * m2[4 + c] + hv.z * m2[8 + c] + hv.w * m2[12 + c];
    float sc0 = scl[4*r]   + hv.x*vb[4]  + hv.y*vb[5]  + hv.z*vb[6]  + hv.w*vb[7];
    float sc1 = scl[4*r+1] + hv.x*vb[8]  + hv.y*vb[9]  + hv.z*vb[10] + hv.w*vb[11];
    float scb = scl[4*r+2] + hv.x*vb[12] + hv.y*vb[13] + hv.z*vb[14] + hv.w*vb[15];
    ((float4*)ug)[idx] = make_float4(u[0], u[1], u[2], u[3]);
    ((float4*)scal)[idx] = make_float4(sc0, sc1, scb, 0.f);
}

// ---- layer1 per-dst prep: tiled GEMM  u[idx][0..63] = M2 h_d + bias -------
__global__ __launch_bounds__(256) void dstprep_g(
    const float* __restrict__ h, const float* __restrict__ M2T,
    const float* __restrict__ vec4, float* __restrict__ ug)
{
    __shared__ float sIn[64 * 64];
    __shared__ float sW[64 * 64];
    int blk = blockIdx.x, tid = threadIdx.x;
    int r = 0;
    while (r < NREL - 1 && blk >= d_qwoff[r + 1]) ++r;
    int l0 = (blk - d_qwoff[r]) * 64;
    int nd = d_qoff[r + 1] - d_qoff[r];
    stage_in<64>(sIn, h + (long)d_dlo[r] * 64, l0, nd, tid);
    stage_w<64>(sW, M2T + (long)r * 4096, tid);
    __syncthreads();
    int tx = tid & 15, ty = tid >> 4;
    int r0 = ty * 4, c0 = tx * 4;
    float4 bias = *(const float4*)(vec4 + (long)r * 256 + c0);
    float acc[4][4];
    #pragma unroll
    for (int i = 0; i < 4; ++i) {
        acc[i][0] = bias.x; acc[i][1] = bias.y; acc[i][2] = bias.z; acc[i][3] = bias.w;
    }
    mma_t<64>(acc, sIn, sW, r0, c0);
    #pragma unroll
    for (int i = 0; i < 4; ++i) {
        int lr = l0 + r0 + i;
        if (lr < nd)
            *(float4*)(ug + (long)(d_qoff[r] + lr) * 64 + c0) =
                make_float4(acc[i][0], acc[i][1], acc[i][2], acc[i][3]);
    }
}

// ---- layer1 per-dst scalars: wave/node, lane=k, coalesced -----------------
__global__ __launch_bounds__(256) void scal64(
    const float* __restrict__ h, const float* __restrict__ vec4,
    const float* __restrict__ scl, float* __restrict__ scal)
{
    int wv   = (blockIdx.x * blockDim.x + threadIdx.x) >> 6;
    int lane = threadIdx.x & 63;
    if (wv >= NQ) return;
    int r = 0;
    while (r < NREL - 1 && wv >= d_qoff[r + 1]) ++r;
    int node = d_dlo[r] + (wv - d_qoff[r]);
    float hv = h[(long)node * 64 + lane];
    float s0 = hv * vec4[(long)r * 256 + 64 + lane];
    float s1 = hv * vec4[(long)r * 256 + 128 + lane];
    float s2 = hv * vec4[(long)r * 256 + 192 + lane];
    #pragma unroll
    for (int m = 32; m > 0; m >>= 1) {
        s0 += __shfl_xor(s0, m);
        s1 += __shfl_xor(s1, m);
        s2 += __shfl_xor(s2, m);
    }
    if (lane == 0)
        ((float4*)scal)[wv] = make_float4(s0 + scl[4*r], s1 + scl[4*r+1], s2 + scl[4*r+2], 0.f);
}

// ---- CSR build (static graph) ---------------------------------------------
__global__ __launch_bounds__(256) void csr_count(
    const int* __restrict__ edst, int* __restrict__ cur)
{
    int tid = blockIdx.x * blockDim.x + threadIdx.x;
    if (tid >= NEDGE) return;
    int r = tid / NE;
    atomicAdd(&cur[d_qoff[r] + edst[tid] - d_dlo[r]], 1);
}

__global__ __launch_bounds__(1024) void scan1(
    const int* __restrict__ cur, int* __restrict__ rowst, int* __restrict__ bsum)
{
    __shared__ int s[1024];
    int t = threadIdx.x, g = blockIdx.x * 1024 + t;
    s[t] = g < NQ ? cur[g] : 0;
    __syncthreads();
    for (int o = 1; o < 1024; o <<= 1) {
        int x = t >= o ? s[t - o] : 0;
        __syncthreads();
        s[t] += x;
        __syncthreads();
    }
    if (g < NQ) rowst[g + 1] = s[t];
    if (t == 1023) bsum[blockIdx.x] = s[1023];
}

__global__ __launch_bounds__(512) void scan2(int* __restrict__ bsum)
{
    __shared__ int s[512];
    int t = threadIdx.x;
    s[t] = t < NB1 ? bsum[t] : 0;
    __syncthreads();
    for (int o = 1; o < 512; o <<= 1) {
        int x = t >= o ? s[t - o] : 0;
        __syncthreads();
        s[t] += x;
        __syncthreads();
    }
    if (t < NB1) bsum[t] = (t == 0) ? 0 : s[t - 1];
}

__global__ __launch_bounds__(256) void scan3(
    const int* __restrict__ bsum, int* __restrict__ rowst)
{
    int g = blockIdx.x * blockDim.x + threadIdx.x;
    if (g == 0) rowst[0] = 0;
    if (g < NQ) rowst[g + 1] += bsum[g >> 10];
}

__global__ __launch_bounds__(256) void csr_fill(
    const int* __restrict__ edst, const int* __restrict__ rowst,
    int* __restrict__ cur, int* __restrict__ elist)
{
    int tid = blockIdx.x * blockDim.x + threadIdx.x;
    if (tid >= NEDGE) return;
    int r = tid / NE;
    int idx = d_qoff[r] + edst[tid] - d_dlo[r];
    int pos = rowst[idx] + atomicAdd(&cur[idx], 1);
    elist[pos] = tid;
}

// ---- edge alpha: alpha = 0.125*(h_s.u_d + cb + ea0 c0 + ea1 c1) -----------
__global__ __launch_bounds__(256) void edge_alpha_t4(
    const float* __restrict__ h, const float* __restrict__ ug,
    const float* __restrict__ scal,
    const int* __restrict__ esrc, const int* __restrict__ edst,
    const float* __restrict__ eattr, float* __restrict__ alphab)
{
    int e = blockIdx.x * blockDim.x + threadIdx.x;
    if (e >= NEDGE) return;
    int r = e / NE;
    long idx = d_qoff[r] + edst[e] - d_dlo[r];
    float4 hs = ((const float4*)h)[esrc[e]];
    float4 ud = ((const float4*)ug)[idx];
    float4 sc = ((const float4*)scal)[idx];
    float ea0 = eattr[2 * (long)e], ea1 = eattr[2 * (long)e + 1];
    float p = hs.x*ud.x + hs.y*ud.y + hs.z*ud.z + hs.w*ud.w
            + sc.z + ea0 * sc.x + ea1 * sc.y;
    alphab[e] = 0.125f * p;
}

__global__ __launch_bounds__(256) void edge_alpha_w(
    const float* __restrict__ h, const float* __restrict__ ug,
    const float* __restrict__ scal,
    const int* __restrict__ esrc, const int* __restrict__ edst,
    const float* __restrict__ eattr, float* __restrict__ alphab)
{
    int e    = (blockIdx.x * blockDim.x + threadIdx.x) >> 6;
    int lane = threadIdx.x & 63;
    if (e >= NEDGE) return;
    int r = e / NE;
    long idx = d_qoff[r] + edst[e] - d_dlo[r];
    float p = h[(long)esrc[e] * 64 + lane] * ug[idx * 64 + lane];
    #pragma unroll
    for (int m = 32; m > 0; m >>= 1) p += __shfl_xor(p, m);
    if (lane == 0) {
        float4 sc = ((const float4*)scal)[idx];
        float ea0 = eattr[2 * (long)e], ea1 = eattr[2 * (long)e + 1];
        alphab[e] = 0.125f * (p + sc.z + ea0 * sc.x + ea1 * sc.y);
    }
}

// ---- gather: g_d = sum_e w_e h_s ; m_d = sum_e w_e ea  (normalized) -------
__global__ __launch_bounds__(256) void gather_t4(
    const float* __restrict__ h, const int* __restrict__ esrc,
    const float* __restrict__ eattr, const float* __restrict__ alphab,
    const int* __restrict__ rowst, const int* __restrict__ elist,
    float* __restrict__ ug, float* __restrict__ gm)
{
    int idx = blockIdx.x * blockDim.x + threadIdx.x;
    if (idx >= NQ) return;
    int e0 = rowst[idx], e1 = rowst[idx + 1];
    if (e0 == e1) {
        ((float4*)ug)[idx] = make_float4(0.f,0.f,0.f,0.f);
        gm[2 * (long)idx] = 0.f; gm[2 * (long)idx + 1] = 0.f;
        return;
    }
    float m = -3.4e38f;
    for (int e = e0; e < e1; ++e) m = fmaxf(m, alphab[elist[e]]);
    float den = 0.f, m0 = 0.f, m1 = 0.f;
    float gx = 0.f, gy = 0.f, gz = 0.f, gw = 0.f;
    for (int e = e0; e < e1; ++e) {
        int eid = elist[e];
        float a = expf(alphab[eid] - m);
        den += a;
        float4 hs = ((const float4*)h)[esrc[eid]];
        gx = fmaf(a, hs.x, gx); gy = fmaf(a, hs.y, gy);
        gz = fmaf(a, hs.z, gz); gw = fmaf(a, hs.w, gw);
        m0 = fmaf(a, eattr[2 * (long)eid],     m0);
        m1 = fmaf(a, eattr[2 * (long)eid + 1], m1);
    }
    float inv = 1.f / (den + 1e-16f);
    ((float4*)ug)[idx] = make_float4(gx*inv, gy*inv, gz*inv, gw*inv);
    gm[2 * (long)idx] = m0 * inv; gm[2 * (long)idx + 1] = m1 * inv;
}

__global__ __launch_bounds__(256) void gather_w(
    const float* __restrict__ h, const int* __restrict__ esrc,
    const float* __restrict__ eattr, const float* __restrict__ alphab,
    const int* __restrict__ rowst, const int* __restrict__ elist,
    float* __restrict__ ug, float* __restrict__ gm)
{
    int idx  = (blockIdx.x * blockDim.x + threadIdx.x) >> 6;
    int lane = threadIdx.x & 63;
    if (idx >= NQ) return;
    int e0 = rowst[idx], e1 = rowst[idx + 1];
    if (e0 == e1) {
        ug[(long)idx * 64 + lane] = 0.f;
        if (lane == 0) { gm[2*(long)idx] = 0.f; gm[2*(long)idx+1] = 0.f; }
        return;
    }
    float m = -3.4e38f;
    for (int e = e0; e < e1; ++e) m = fmaxf(m, alphab[elist[e]]);
    float den = 0.f, m0 = 0.f, m1 = 0.f, g = 0.f;
    for (int e = e0; e < e1; ++e) {
        int eid = elist[e];
        float a = expf(alphab[eid] - m);
        den += a;
        g  = fmaf(a, h[(long)esrc[eid] * 64 + lane], g);
        m0 = fmaf(a, eattr[2 * (long)eid],     m0);
        m1 = fmaf(a, eattr[2 * (long)eid + 1], m1);
    }
    float inv = 1.f / (den + 1e-16f);
    ug[(long)idx * 64 + lane] = g * inv;
    if (lane == 0) { gm[2*(long)idx] = m0 * inv; gm[2*(long)idx+1] = m1 * inv; }
}

// ---- combine (tiled): out = h@Wc + sum_r [ g@Wv + rank-1 terms ] ----------
template<int K, int RELU>
__global__ __launch_bounds__(256) void combine_g(
    const float* __restrict__ h, const float* __restrict__ Wc,
    const float* __restrict__ bs, const float* __restrict__ Wv,
    const float* __restrict__ bv, const float* __restrict__ We,
    const float* __restrict__ ug, const float* __restrict__ gm,
    const int* __restrict__ rowst, float* __restrict__ outp)
{
    __shared__ float sIn[K * 64];
    __shared__ float sW[K * 64];
    __shared__ float sHe[64], sG0[64], sG1[64];
    int blk = blockIdx.x, tid = threadIdx.x;
    int t = 0;
    while (t < 3 && blk >= d_twoff[t + 1]) ++t;
    int l0 = (blk - d_twoff[t]) * 64;
    int nt = d_tbase[t + 1] - d_tbase[t];
    int tx = tid & 15, ty = tid >> 4;
    int r0 = ty * 4, c0 = tx * 4;
    float acc[4][4];
    #pragma unroll
    for (int i = 0; i < 4; ++i) {
        acc[i][0] = 0.f; acc[i][1] = 0.f; acc[i][2] = 0.f; acc[i][3] = 0.f;
    }
    // skip segment: h @ Wc[t]
    stage_in<K>(sIn, h + (long)d_tbase[t] * K, l0, nt, tid);
    stage_w<K>(sW, Wc + (long)t * K * 64, tid);
    __syncthreads();
    mma_t<K>(acc, sIn, sW, r0, c0);
    int nr = d_ntrel[t];
    for (int ri = 0; ri < nr; ++ri) {
        int rr = d_trel[t][ri];
        __syncthreads();                       // protect LDS before restage
        stage_in<K>(sIn, ug + (long)d_qoff[rr] * K, l0, nt, tid);
        stage_w<K>(sW, Wv + (long)rr * K * 64, tid);
        if (tid < 64) {
            int lcl = min(l0 + tid, nt - 1);
            long idx = d_qoff[rr] + lcl;
            sHe[tid] = (rowst[idx + 1] > rowst[idx]) ? 1.f : 0.f;
            sG0[tid] = gm[2 * idx];
            sG1[tid] = gm[2 * idx + 1];
        }
        __syncthreads();
        mma_t<K>(acc, sIn, sW, r0, c0);
        float4 bsr = *(const float4*)(bs + rr * 64 + c0);
        float4 bvr = *(const float4*)(bv + rr * 64 + c0);
        float4 w0  = *(const float4*)(We + rr * 128 + c0);
        float4 w1  = *(const float4*)(We + rr * 128 + 64 + c0);
        #pragma unroll
        for (int i = 0; i < 4; ++i) {
            float he = sHe[r0 + i], g0 = sG0[r0 + i], g1 = sG1[r0 + i];
            acc[i][0] += bsr.x + he * bvr.x + g0 * w0.x + g1 * w1.x;
            acc[i][1] += bsr.y + he * bvr.y + g0 * w0.y + g1 * w1.y;
            acc[i][2] += bsr.z + he * bvr.z + g0 * w0.z + g1 * w1.z;
            acc[i][3] += bsr.w + he * bvr.w + g0 * w0.w + g1 * w1.w;
        }
    }
    #pragma unroll
    for (int i = 0; i < 4; ++i) {
        int lr = l0 + r0 + i;
        if (lr < nt) {
            float4 v = make_float4(acc[i][0], acc[i][1], acc[i][2], acc[i][3]);
            if (RELU) {
                v.x = fmaxf(v.x, 0.f); v.y = fmaxf(v.y, 0.f);
                v.z = fmaxf(v.z, 0.f); v.w = fmaxf(v.w, 0.f);
            }
            *(float4*)(outp + (long)(d_tbase[t] + lr) * 64 + c0) = v;
        }
    }
}

// ---- head / power flow / final --------------------------------------------
__global__ __launch_bounds__(256) void head(
    const float* __restrict__ acc, const float* __restrict__ Wlin,
    float* __restrict__ out4)
{
    int wid  = (blockIdx.x * blockDim.x + threadIdx.x) >> 6;
    int lane = threadIdx.x & 63;
    if (wid >= NN) return;
    float hv = fmaxf(acc[(long)wid * 64 + lane], 0.f);
    float4 w = ((const float4*)Wlin)[lane];
    float p0 = hv * w.x, p1 = hv * w.y, p2 = hv * w.z, p3 = hv * w.w;
    #pragma unroll
    for (int m = 32; m > 0; m >>= 1) {
        p0 += __shfl_xor(p0, m);
        p1 += __shfl_xor(p1, m);
        p2 += __shfl_xor(p2, m);
        p3 += __shfl_xor(p3, m);
    }
    if (lane == 0) {
        out4[4 * (long)wid + 0] = p0;
        out4[4 * (long)wid + 1] = p1;
        out4[4 * (long)wid + 2] = p2;
        out4[4 * (long)wid + 3] = p3;
    }
}

__global__ __launch_bounds__(256) void pf_accum(
    const int* __restrict__ pfi, const int* __restrict__ pfj,
    const float* __restrict__ pfa, const float* __restrict__ out4,
    float* __restrict__ Pb, float* __restrict__ Qp)
{
    int e = blockIdx.x * blockDim.x + threadIdx.x;
    if (e >= EPF) return;
    int i = pfi[e], j = pfj[e];
    float r = pfa[2 * (long)e], x = pfa[2 * (long)e + 1];
    float dn = r * r + x * x;
    float G = r / dn, B = -x / dn;
    float thi = out4[4 * (long)i + 1], thj = out4[4 * (long)j + 1];
    float Vi = fabsf(out4[4 * (long)i]), Vj = fabsf(out4[4 * (long)j]);
    float dlt = thj - thi;
    float cd = cosf(dlt), sd = sinf(dlt);
    float vv = Vi * Vj;
    atomicAdd(&Pb[i], vv * (G * cd + B * sd));
    atomicAdd(&Qp[i], vv * (G * sd - B * cd));
}

__global__ __launch_bounds__(256) void final_out(
    const float* __restrict__ out4, const float* __restrict__ cons,
    const float* __restrict__ xin, const float* __restrict__ Pb,
    const float* __restrict__ Qp, float* __restrict__ out)
{
    int n = blockIdx.x * blockDim.x + threadIdx.x;
    if (n >= NN) return;
    const float* c = cons + 7 * (long)n;
    float th = out4[4 * (long)n + 1];
    float V  = fabsf(out4[4 * (long)n + 0]);
    float o0 = csig(V, c[0], c[1]) / xin[4 * (long)n + 0];
    float o2 = csig(Pb[n], c[3], c[4]);
    float o3 = csig(Qp[n], c[5], c[6]);
    out[4 * (long)n + 0] = o0;
    out[4 * (long)n + 1] = th;
    out[4 * (long)n + 2] = o2;
    out[4 * (long)n + 3] = o3;
}

extern "C" void kernel_launch(void* const* d_in, const int* in_sizes, int n_in,
                              void* d_out, int out_size, void* d_ws, size_t ws_size,
                              hipStream_t stream) {
    const float* xin  = (const float*)d_in[0];
    const float* cons = (const float*)d_in[1];
    const int*   esrc = (const int*)d_in[2];
    const int*   edst = (const int*)d_in[3];
    const float* eatt = (const float*)d_in[4];
    const int*   pfi  = (const int*)d_in[5];
    const int*   pfj  = (const int*)d_in[6];
    const float* pfa  = (const float*)d_in[7];

    const float* Wlin;
    int wb;
    if (in_sizes[8] == 256) { Wlin = (const float*)d_in[8];  wb = 9; }
    else                    { Wlin = (const float*)d_in[26]; wb = 8; }
    const float* Wq0 = (const float*)d_in[wb + 0];
    const float* bq0 = (const float*)d_in[wb + 1];
    const float* Wk0 = (const float*)d_in[wb + 2];
    const float* bk0 = (const float*)d_in[wb + 3];
    const float* Wv0 = (const float*)d_in[wb + 4];
    const float* bv0 = (const float*)d_in[wb + 5];
    const float* We0 = (const float*)d_in[wb + 6];
    const float* Ws0 = (const float*)d_in[wb + 7];
    const float* bs0 = (const float*)d_in[wb + 8];
    const float* Wq1 = (const float*)d_in[wb + 9];
    const float* bq1 = (const float*)d_in[wb + 10];
    const float* Wk1 = (const float*)d_in[wb + 11];
    const float* bk1 = (const float*)d_in[wb + 12];
    const float* Wv1 = (const float*)d_in[wb + 13];
    const float* bv1 = (const float*)d_in[wb + 14];
    const float* We1 = (const float*)d_in[wb + 15];
    const float* Ws1 = (const float*)d_in[wb + 16];
    const float* bs1 = (const float*)d_in[wb + 17];

    // ---- workspace layout (~170 MB) ----
    float* w = (float*)d_ws;
    size_t off = 0;
    float* h1     = w + off; off += (size_t)NN * 64;
    float* acc    = w + off; off += (size_t)NN * 64;
    float* ug     = w + off; off += (size_t)NQ * 64;        // u then g
    float* scal   = w + off; off += (size_t)NQ * 4;
    float* gm     = w + off; off += (size_t)NQ * 2;
    float* alphab = w + off; off += (size_t)NEDGE;
    int*   rowst  = (int*)(w + off); off += NQ + 1;
    int*   cur    = (int*)(w + off); off += NQ;
    int*   bsum   = (int*)(w + off); off += 512;
    int*   elist  = (int*)(w + off); off += NEDGE;
    float* M2T    = w + off; off += (size_t)NREL * 64 * 64;
    float* vec4   = w + off; off += (size_t)NREL * 4 * 64;
    float* sclr   = w + off; off += NREL * 4;
    float* Wc0    = w + off; off += 4 * 4 * 64;
    float* Wc1    = w + off; off += 4 * 64 * 64;
    float* Pb     = w + off; off += NN;
    float* Qp     = w + off; off += NN;
    float* out4   = w + off; off += (size_t)NN * 4;
    if (ws_size < off * sizeof(float)) return;

    const int eaWBlocks  = (NEDGE + 3) / 4;
    const int gaWBlocks  = (NQ + 3) / 4;
    const int nodeWaveBlks = (NN + 3) / 4;

    hipMemsetAsync(cur, 0, (size_t)NQ * 4, stream);
    hipMemsetAsync(Pb,  0, (size_t)NN * 4, stream);
    hipMemsetAsync(Qp,  0, (size_t)NN * 4, stream);

    combine_skip<4> <<<(4*4*64 + 255)/256, 256, 0, stream>>>(Ws0, Wc0);
    combine_skip<64><<<(4*64*64 + 255)/256, 256, 0, stream>>>(Ws1, Wc1);

    // CSR (static graph, shared by both layers)
    csr_count<<<(NEDGE + 255)/256, 256, 0, stream>>>(edst, cur);
    scan1<<<NB1, 1024, 0, stream>>>(cur, rowst, bsum);
    scan2<<<1, 512, 0, stream>>>(bsum);
    scan3<<<(NQ + 255)/256, 256, 0, stream>>>(bsum, rowst);
    hipMemsetAsync(cur, 0, (size_t)NQ * 4, stream);
    csr_fill<<<(NEDGE + 255)/256, 256, 0, stream>>>(edst, rowst, cur, elist);

    // ================= layer 0 (din=4, h = x) =================
    mk_m2t<4><<<(NREL*16 + 255)/256, 256, 0, stream>>>(Wk0, Wq0, M2T);
    mk_vecs<4><<<(NREL*16 + 255)/256, 256, 0, stream>>>(Wk0, Wq0, bq0, bk0, We0, vec4);
    mk_scl<<<1, 64, 0, stream>>>(bq0, bk0, We0, sclr);
    dstprep4<<<(NQ + 255)/256, 256, 0, stream>>>(xin, M2T, vec4, sclr, ug, scal);
    edge_alpha_t4<<<(NEDGE + 255)/256, 256, 0, stream>>>(xin, ug, scal, esrc, edst, eatt, alphab);
    gather_t4<<<(NQ + 255)/256, 256, 0, stream>>>(xin, esrc, eatt, alphab, rowst, elist, ug, gm);
    combine_g<4,1><<<TWAVES, 256, 0, stream>>>(xin, Wc0, bs0, Wv0, bv0, We0, ug, gm, rowst, h1);

    // ================= layer 1 (din=64, h = h1) =================
    mk_m2t<64><<<(NREL*64*64 + 255)/256, 256, 0, stream>>>(Wk1, Wq1, M2T);
    mk_vecs<64><<<(NREL*4*64 + 255)/256, 256, 0, stream>>>(Wk1, Wq1, bq1, bk1, We1, vec4);
    mk_scl<<<1, 64, 0, stream>>>(bq1, bk1, We1, sclr);
    dstprep_g<<<QWAVES, 256, 0, stream>>>(h1, M2T, vec4, ug);
    scal64<<<gaWBlocks, 256, 0, stream>>>(h1, vec4, sclr, scal);
    edge_alpha_w<<<eaWBlocks, 256, 0, stream>>>(h1, ug, scal, esrc, edst, eatt, alphab);
    gather_w<<<gaWBlocks, 256, 0, stream>>>(h1, esrc, eatt, alphab, rowst, elist, ug, gm);
    combine_g<64,0><<<TWAVES, 256, 0, stream>>>(h1, Wc1, bs1, Wv1, bv1, We1, ug, gm, rowst, acc);

    // ================= head + power flow + final =================
    head<<<nodeWaveBlks, 256, 0, stream>>>(acc, Wlin, out4);
    pf_accum<<<(EPF + 255)/256, 256, 0, stream>>>(pfi, pfj, pfa, out4, Pb, Qp);
    final_out<<<(NN + 255)/256, 256, 0, stream>>>(out4, cons, xin, Pb, Qp, (float*)d_out);
}

// Round 11
// 847.504 us; speedup vs baseline: 3.8318x; 1.5583x over previous
//
#include <hip/hip_runtime.h>
#include <hip/hip_bf16.h>

#define NREL 14
#define NE     100000
#define NEDGE  (NREL*NE)
#define NN     100000
#define EPF    800000
#define NQ     370000                 // sum of dst-range sizes over relations
#define NB1    ((NQ + 1023) / 1024)   // scan blocks = 362
#define QWAVES 5786                   // sum ceil(nd/64) (also GEMM blocks)
#define TWAVES 1564                   // sum ceil(typesize/64)

__device__ __constant__ int d_dlo[NREL]   = {10000,30000,70000,30000,70000,70000,0,0,0,10000,30000,10000,30000,70000};
__device__ __constant__ int d_qoff[NREL+1]= {0,20000,60000,90000,130000,160000,190000,200000,210000,220000,240000,280000,300000,340000,370000};
__device__ __constant__ int d_qwoff[NREL+1]={0,313,938,1407,2032,2501,2970,3127,3284,3441,3754,4379,4692,5317,5786};
__device__ __constant__ int d_trel[4][4]  = {{6,7,8,-1},{0,9,11,-1},{1,3,10,12},{2,4,5,13}};
__device__ __constant__ int d_ntrel[4]    = {3,3,4,4};
__device__ __constant__ int d_tbase[5]    = {0,10000,30000,70000,100000};
__device__ __constant__ int d_twoff[5]    = {0,157,470,1095,1564};

__device__ __forceinline__ float csig(float v, float lo, float hi) {
    float mid = 0.5f * (lo + hi);
    float s = 1.0f / (1.0f + expf(-0.1f * (v - mid)));
    return (s - 0.5f) * (hi - lo) + mid;
}

// ==================== tiled-GEMM building blocks ===========================
template<int K>
__device__ __forceinline__ void stage_in(
    float* sIn, const float* __restrict__ src, int l0, int n, int tid)
{
    if (K == 4) {
        if (tid < 64) {
            int lcl = min(l0 + tid, n - 1);
            float4 v = *(const float4*)(src + (long)lcl * 4);
            sIn[0 * 64 + tid] = v.x; sIn[1 * 64 + tid] = v.y;
            sIn[2 * 64 + tid] = v.z; sIn[3 * 64 + tid] = v.w;
        }
    } else {
        int row = tid >> 2, q = tid & 3;
        int lcl = min(l0 + row, n - 1);
        const float* p = src + (long)lcl * 64 + q * 16;
        #pragma unroll
        for (int kk = 0; kk < 4; ++kk) {
            float4 v = *(const float4*)(p + kk * 4);
            int k = q * 16 + kk * 4;
            sIn[(k + 0) * 64 + row] = v.x;
            sIn[(k + 1) * 64 + row] = v.y;
            sIn[(k + 2) * 64 + row] = v.z;
            sIn[(k + 3) * 64 + row] = v.w;
        }
    }
}

template<int K>
__device__ __forceinline__ void stage_w(
    float* sW, const float* __restrict__ src, int tid)
{
    for (int i = tid * 4; i < K * 64; i += 1024)
        *(float4*)(sW + i) = *(const float4*)(src + i);
}

template<int K>
__device__ __forceinline__ void mma_t(
    float acc[4][4], const float* sIn, const float* sW, int r0, int c0)
{
    for (int k = 0; k < K; ++k) {
        float4 a = *(const float4*)(sIn + k * 64 + r0);
        float4 b = *(const float4*)(sW + k * 64 + c0);
        acc[0][0] = fmaf(a.x, b.x, acc[0][0]);
        acc[0][1] = fmaf(a.x, b.y, acc[0][1]);
        acc[0][2] = fmaf(a.x, b.z, acc[0][2]);
        acc[0][3] = fmaf(a.x, b.w, acc[0][3]);
        acc[1][0] = fmaf(a.y, b.x, acc[1][0]);
        acc[1][1] = fmaf(a.y, b.y, acc[1][1]);
        acc[1][2] = fmaf(a.y, b.z, acc[1][2]);
        acc[1][3] = fmaf(a.y, b.w, acc[1][3]);
        acc[2][0] = fmaf(a.z, b.x, acc[2][0]);
        acc[2][1] = fmaf(a.z, b.y, acc[2][1]);
        acc[2][2] = fmaf(a.z, b.z, acc[2][2]);
        acc[2][3] = fmaf(a.z, b.w, acc[2][3]);
        acc[3][0] = fmaf(a.w, b.x, acc[3][0]);
        acc[3][1] = fmaf(a.w, b.y, acc[3][1]);
        acc[3][2] = fmaf(a.w, b.z, acc[3][2]);
        acc[3][3] = fmaf(a.w, b.w, acc[3][3]);
    }
}

// ---- combined skip weights: Wc[t] = sum_{r: dst_type==t} Ws[r] -------------
template<int DIN>
__global__ __launch_bounds__(256) void combine_skip(
    const float* __restrict__ Ws, float* __restrict__ Wc)
{
    int tid = blockIdx.x * blockDim.x + threadIdx.x;
    if (tid >= 4 * DIN * 64) return;
    int t = tid / (DIN * 64), o = tid % (DIN * 64);
    float s = 0.f;
    for (int ri = 0; ri < d_ntrel[t]; ++ri) s += Ws[d_trel[t][ri] * DIN * 64 + o];
    Wc[tid] = s;
}

// ---- relation prep ---------------------------------------------------------
template<int DIN>
__global__ __launch_bounds__(256) void mk_m2t(
    const float* __restrict__ Wk, const float* __restrict__ Wq,
    float* __restrict__ M2T)
{
    int tid = blockIdx.x * blockDim.x + threadIdx.x;
    if (tid >= NREL * DIN * DIN) return;
    int r = tid / (DIN * DIN), rem = tid % (DIN * DIN);
    int i = rem / DIN, j = rem % DIN;
    const float* wki = Wk + (long)r * DIN * 64 + i * 64;
    const float* wqj = Wq + (long)r * DIN * 64 + j * 64;
    float s = 0.f;
    for (int c = 0; c < 64; ++c) s = fmaf(wki[c], wqj[c], s);
    M2T[(long)r * DIN * DIN + j * DIN + i] = s;
}

// vec4[r][k][i]: k=0: Wk bq (u init); k=1: Wq we0; k=2: Wq we1; k=3: Wq bk
template<int DIN>
__global__ __launch_bounds__(256) void mk_vecs(
    const float* __restrict__ Wk, const float* __restrict__ Wq,
    const float* __restrict__ bq, const float* __restrict__ bk,
    const float* __restrict__ We, float* __restrict__ vec4)
{
    int tid = blockIdx.x * blockDim.x + threadIdx.x;
    if (tid >= NREL * 4 * DIN) return;
    int r = tid / (4 * DIN), rem = tid % (4 * DIN);
    int k = rem / DIN, i = rem % DIN;
    const float* row; const float* v;
    if (k == 0) { row = Wk + (long)r * DIN * 64 + i * 64; v = bq + r * 64; }
    else {
        row = Wq + (long)r * DIN * 64 + i * 64;
        v = (k == 1) ? We + r * 128 : (k == 2) ? We + r * 128 + 64 : bk + r * 64;
    }
    float s = 0.f;
    for (int c = 0; c < 64; ++c) s = fmaf(row[c], v[c], s);
    vec4[tid] = s;
}

// scl[r] = (bq.we0, bq.we1, bk.bq, 0)
__global__ __launch_bounds__(64) void mk_scl(
    const float* __restrict__ bq, const float* __restrict__ bk,
    const float* __restrict__ We, float* __restrict__ scl)
{
    int r = blockIdx.x * blockDim.x + threadIdx.x;
    if (r >= NREL) return;
    float s0 = 0.f, s1 = 0.f, sb = 0.f;
    for (int c = 0; c < 64; ++c) {
        float b = bq[r * 64 + c];
        s0 = fmaf(b, We[r * 128 + c], s0);
        s1 = fmaf(b, We[r * 128 + 64 + c], s1);
        sb = fmaf(b, bk[r * 64 + c], sb);
    }
    scl[4 * r] = s0; scl[4 * r + 1] = s1; scl[4 * r + 2] = sb; scl[4 * r + 3] = 0.f;
}

// ---- layer0 per-dst prep (din=4): u float4 + scal -------------------------
__global__ __launch_bounds__(256) void dstprep4(
    const float* __restrict__ h, const float* __restrict__ M2T,
    const float* __restrict__ vec4, const float* __restrict__ scl,
    float* __restrict__ ug, float* __restrict__ scal)
{
    int idx = blockIdx.x * blockDim.x + threadIdx.x;
    if (idx >= NQ) return;
    int r = 0;
    while (r < NREL - 1 && idx >= d_qoff[r + 1]) ++r;
    int node = d_dlo[r] + (idx - d_qoff[r]);
    float4 hv = ((const float4*)h)[node];
    const float* m2 = M2T + (long)r * 16;
    const float* vb = vec4 + (long)r * 16;
    float u[4];
    #pragma unroll
    for (int c = 0; c < 4; ++c)
        u[c] = vb[c] + hv.x * m2[c] + hv.y * m2[4 + c] + hv.z * m2[8 + c] + hv.w * m2[12 + c];
    float sc0 = scl[4*r]   + hv.x*vb[4]  + hv.y*vb[5]  + hv.z*vb[6]  + hv.w*vb[7];
    float sc1 = scl[4*r+1] + hv.x*vb[8]  + hv.y*vb[9]  + hv.z*vb[10] + hv.w*vb[11];
    float scb = scl[4*r+2] + hv.x*vb[12] + hv.y*vb[13] + hv.z*vb[14] + hv.w*vb[15];
    ((float4*)ug)[idx] = make_float4(u[0], u[1], u[2], u[3]);
    ((float4*)scal)[idx] = make_float4(sc0, sc1, scb, 0.f);
}

// ---- layer1 per-dst prep: tiled GEMM u = M2 h_d + bias; + scal fold -------
__global__ __launch_bounds__(256) void dstprep_g(
    const float* __restrict__ h, const float* __restrict__ M2T,
    const float* __restrict__ vec4, const float* __restrict__ scl,
    float* __restrict__ ug, float* __restrict__ scal)
{
    __shared__ float sIn[64 * 64];
    __shared__ float sW[64 * 64];
    int blk = blockIdx.x, tid = threadIdx.x;
    int r = 0;
    while (r < NREL - 1 && blk >= d_qwoff[r + 1]) ++r;
    int l0 = (blk - d_qwoff[r]) * 64;
    int nd = d_qoff[r + 1] - d_qoff[r];
    stage_in<64>(sIn, h + (long)d_dlo[r] * 64, l0, nd, tid);
    stage_w<64>(sW, M2T + (long)r * 4096, tid);
    __syncthreads();
    int tx = tid & 15, ty = tid >> 4;
    int r0 = ty * 4, c0 = tx * 4;
    float4 bias = *(const float4*)(vec4 + (long)r * 256 + c0);
    float acc[4][4];
    #pragma unroll
    for (int i = 0; i < 4; ++i) {
        acc[i][0] = bias.x; acc[i][1] = bias.y; acc[i][2] = bias.z; acc[i][3] = bias.w;
    }
    mma_t<64>(acc, sIn, sW, r0, c0);
    #pragma unroll
    for (int i = 0; i < 4; ++i) {
        int lr = l0 + r0 + i;
        if (lr < nd)
            *(float4*)(ug + (long)(d_qoff[r] + lr) * 64 + c0) =
                make_float4(acc[i][0], acc[i][1], acc[i][2], acc[i][3]);
    }
    // per-dst scalars from the staged h tile (wave 0)
    if (tid < 64) {
        const float* w1p = vec4 + (long)r * 256 + 64;
        const float* w2p = vec4 + (long)r * 256 + 128;
        const float* w3p = vec4 + (long)r * 256 + 192;
        float s0 = 0.f, s1 = 0.f, s2 = 0.f;
        for (int k = 0; k < 64; ++k) {
            float hv = sIn[k * 64 + tid];
            s0 = fmaf(hv, w1p[k], s0);
            s1 = fmaf(hv, w2p[k], s1);
            s2 = fmaf(hv, w3p[k], s2);
        }
        int lr = l0 + tid;
        if (lr < nd)
            ((float4*)scal)[d_qoff[r] + lr] =
                make_float4(s0 + scl[4*r], s1 + scl[4*r+1], s2 + scl[4*r+2], 0.f);
    }
}

// ---- CSR build (static graph) ---------------------------------------------
__global__ __launch_bounds__(256) void csr_count(
    const int* __restrict__ edst, int* __restrict__ cur)
{
    int tid = blockIdx.x * blockDim.x + threadIdx.x;
    if (tid >= NEDGE) return;
    int r = tid / NE;
    atomicAdd(&cur[d_qoff[r] + edst[tid] - d_dlo[r]], 1);
}

__global__ __launch_bounds__(1024) void scan1(
    const int* __restrict__ cur, int* __restrict__ rowst, int* __restrict__ bsum)
{
    __shared__ int s[1024];
    int t = threadIdx.x, g = blockIdx.x * 1024 + t;
    s[t] = g < NQ ? cur[g] : 0;
    __syncthreads();
    for (int o = 1; o < 1024; o <<= 1) {
        int x = t >= o ? s[t - o] : 0;
        __syncthreads();
        s[t] += x;
        __syncthreads();
    }
    if (g < NQ) rowst[g + 1] = s[t];
    if (t == 1023) bsum[blockIdx.x] = s[1023];
}

__global__ __launch_bounds__(512) void scan2(int* __restrict__ bsum)
{
    __shared__ int s[512];
    int t = threadIdx.x;
    s[t] = t < NB1 ? bsum[t] : 0;
    __syncthreads();
    for (int o = 1; o < 512; o <<= 1) {
        int x = t >= o ? s[t - o] : 0;
        __syncthreads();
        s[t] += x;
        __syncthreads();
    }
    if (t < NB1) bsum[t] = (t == 0) ? 0 : s[t - 1];
}

__global__ __launch_bounds__(256) void scan3(
    const int* __restrict__ bsum, int* __restrict__ rowst)
{
    int g = blockIdx.x * blockDim.x + threadIdx.x;
    if (g == 0) rowst[0] = 0;
    if (g < NQ) rowst[g + 1] += bsum[g >> 10];
}

__global__ __launch_bounds__(256) void csr_fill(
    const int* __restrict__ edst, const int* __restrict__ rowst,
    int* __restrict__ cur, int* __restrict__ elist)
{
    int tid = blockIdx.x * blockDim.x + threadIdx.x;
    if (tid >= NEDGE) return;
    int r = tid / NE;
    int idx = d_qoff[r] + edst[tid] - d_dlo[r];
    int pos = rowst[idx] + atomicAdd(&cur[idx], 1);
    elist[pos] = tid;
}

// ---- fused edge phase, layer 0: alpha + online softmax + gather (thread/idx)
__global__ __launch_bounds__(256) void gfuse_t4(
    const float* __restrict__ h, const float* __restrict__ scal,
    const int* __restrict__ esrc, const float* __restrict__ eattr,
    const int* __restrict__ rowst, const int* __restrict__ elist,
    float* __restrict__ ug, float* __restrict__ gm)
{
    int idx = blockIdx.x * blockDim.x + threadIdx.x;
    if (idx >= NQ) return;
    int e0 = rowst[idx], e1 = rowst[idx + 1];
    if (e0 == e1) {
        ((float4*)ug)[idx] = make_float4(0.f, 0.f, 0.f, 0.f);
        gm[2 * (long)idx] = 0.f; gm[2 * (long)idx + 1] = 0.f;
        return;
    }
    float4 u = ((const float4*)ug)[idx];
    float4 sc = ((const float4*)scal)[idx];
    float m = -3.4e38f, den = 0.f, m0 = 0.f, m1 = 0.f;
    float gx = 0.f, gy = 0.f, gz = 0.f, gw = 0.f;
    for (int e = e0; e < e1; ++e) {
        int eid = elist[e];
        float4 hs = ((const float4*)h)[esrc[eid]];
        float ea0 = eattr[2 * (long)eid], ea1 = eattr[2 * (long)eid + 1];
        float alpha = 0.125f * (hs.x*u.x + hs.y*u.y + hs.z*u.z + hs.w*u.w
                                + sc.z + ea0 * sc.x + ea1 * sc.y);
        float a;
        if (alpha > m) {
            float s = expf(m - alpha);
            den *= s; gx *= s; gy *= s; gz *= s; gw *= s; m0 *= s; m1 *= s;
            m = alpha; a = 1.f;
        } else {
            a = expf(alpha - m);
        }
        den += a;
        gx = fmaf(a, hs.x, gx); gy = fmaf(a, hs.y, gy);
        gz = fmaf(a, hs.z, gz); gw = fmaf(a, hs.w, gw);
        m0 = fmaf(a, ea0, m0); m1 = fmaf(a, ea1, m1);
    }
    float inv = 1.f / (den + 1e-16f);
    ((float4*)ug)[idx] = make_float4(gx*inv, gy*inv, gz*inv, gw*inv);
    gm[2 * (long)idx] = m0 * inv; gm[2 * (long)idx + 1] = m1 * inv;
}

// ---- fused edge phase, layer 1 (wave/idx, u in register, online softmax) --
__global__ __launch_bounds__(256) void gfuse_w(
    const float* __restrict__ h, const float* __restrict__ scal,
    const int* __restrict__ esrc, const float* __restrict__ eattr,
    const int* __restrict__ rowst, const int* __restrict__ elist,
    float* __restrict__ ug, float* __restrict__ gm)
{
    int idx  = (blockIdx.x * blockDim.x + threadIdx.x) >> 6;
    int lane = threadIdx.x & 63;
    if (idx >= NQ) return;
    int e0 = rowst[idx], e1 = rowst[idx + 1];
    if (e0 == e1) {
        ug[(long)idx * 64 + lane] = 0.f;
        if (lane == 0) { gm[2*(long)idx] = 0.f; gm[2*(long)idx+1] = 0.f; }
        return;
    }
    float u = ug[(long)idx * 64 + lane];
    float4 sc = ((const float4*)scal)[idx];
    float m = -3.4e38f, den = 0.f, m0 = 0.f, m1 = 0.f, g = 0.f;
    int eid = elist[e0];
    for (int e = e0; e < e1; ++e) {
        int eid_next = (e + 1 < e1) ? elist[e + 1] : 0;
        float hs = h[(long)esrc[eid] * 64 + lane];
        float ea0 = eattr[2 * (long)eid], ea1 = eattr[2 * (long)eid + 1];
        float p = hs * u;
        #pragma unroll
        for (int w = 32; w > 0; w >>= 1) p += __shfl_xor(p, w);
        float alpha = 0.125f * (p + sc.z + ea0 * sc.x + ea1 * sc.y);
        float a;
        if (alpha > m) {
            float s = expf(m - alpha);
            den *= s; g *= s; m0 *= s; m1 *= s;
            m = alpha; a = 1.f;
        } else {
            a = expf(alpha - m);
        }
        den += a;
        g  = fmaf(a, hs, g);
        m0 = fmaf(a, ea0, m0);
        m1 = fmaf(a, ea1, m1);
        eid = eid_next;
    }
    float inv = 1.f / (den + 1e-16f);
    ug[(long)idx * 64 + lane] = g * inv;
    if (lane == 0) { gm[2*(long)idx] = m0 * inv; gm[2*(long)idx+1] = m1 * inv; }
}

// ---- combine (tiled): out = h@Wc + sum_r [ g@Wv + rank-1 terms ] ----------
template<int K, int RELU>
__global__ __launch_bounds__(256) void combine_g(
    const float* __restrict__ h, const float* __restrict__ Wc,
    const float* __restrict__ bs, const float* __restrict__ Wv,
    const float* __restrict__ bv, const float* __restrict__ We,
    const float* __restrict__ ug, const float* __restrict__ gm,
    const int* __restrict__ rowst, float* __restrict__ outp)
{
    __shared__ float sIn[K * 64];
    __shared__ float sW[K * 64];
    __shared__ float sHe[64], sG0[64], sG1[64];
    int blk = blockIdx.x, tid = threadIdx.x;
    int t = 0;
    while (t < 3 && blk >= d_twoff[t + 1]) ++t;
    int l0 = (blk - d_twoff[t]) * 64;
    int nt = d_tbase[t + 1] - d_tbase[t];
    int tx = tid & 15, ty = tid >> 4;
    int r0 = ty * 4, c0 = tx * 4;
    float acc[4][4];
    #pragma unroll
    for (int i = 0; i < 4; ++i) {
        acc[i][0] = 0.f; acc[i][1] = 0.f; acc[i][2] = 0.f; acc[i][3] = 0.f;
    }
    stage_in<K>(sIn, h + (long)d_tbase[t] * K, l0, nt, tid);
    stage_w<K>(sW, Wc + (long)t * K * 64, tid);
    __syncthreads();
    mma_t<K>(acc, sIn, sW, r0, c0);
    int nr = d_ntrel[t];
    for (int ri = 0; ri < nr; ++ri) {
        int rr = d_trel[t][ri];
        __syncthreads();
        stage_in<K>(sIn, ug + (long)d_qoff[rr] * K, l0, nt, tid);
        stage_w<K>(sW, Wv + (long)rr * K * 64, tid);
        if (tid < 64) {
            int lcl = min(l0 + tid, nt - 1);
            long idx = d_qoff[rr] + lcl;
            sHe[tid] = (rowst[idx + 1] > rowst[idx]) ? 1.f : 0.f;
            sG0[tid] = gm[2 * idx];
            sG1[tid] = gm[2 * idx + 1];
        }
        __syncthreads();
        mma_t<K>(acc, sIn, sW, r0, c0);
        float4 bsr = *(const float4*)(bs + rr * 64 + c0);
        float4 bvr = *(const float4*)(bv + rr * 64 + c0);
        float4 w0  = *(const float4*)(We + rr * 128 + c0);
        float4 w1  = *(const float4*)(We + rr * 128 + 64 + c0);
        #pragma unroll
        for (int i = 0; i < 4; ++i) {
            float he = sHe[r0 + i], g0 = sG0[r0 + i], g1 = sG1[r0 + i];
            acc[i][0] += bsr.x + he * bvr.x + g0 * w0.x + g1 * w1.x;
            acc[i][1] += bsr.y + he * bvr.y + g0 * w0.y + g1 * w1.y;
            acc[i][2] += bsr.z + he * bvr.z + g0 * w0.z + g1 * w1.z;
            acc[i][3] += bsr.w + he * bvr.w + g0 * w0.w + g1 * w1.w;
        }
    }
    #pragma unroll
    for (int i = 0; i < 4; ++i) {
        int lr = l0 + r0 + i;
        if (lr < nt) {
            float4 v = make_float4(acc[i][0], acc[i][1], acc[i][2], acc[i][3]);
            if (RELU) {
                v.x = fmaxf(v.x, 0.f); v.y = fmaxf(v.y, 0.f);
                v.z = fmaxf(v.z, 0.f); v.w = fmaxf(v.w, 0.f);
            }
            *(float4*)(outp + (long)(d_tbase[t] + lr) * 64 + c0) = v;
        }
    }
}

// ---- head / power flow / final --------------------------------------------
__global__ __launch_bounds__(256) void head(
    const float* __restrict__ acc, const float* __restrict__ Wlin,
    float* __restrict__ out4)
{
    int wid  = (blockIdx.x * blockDim.x + threadIdx.x) >> 6;
    int lane = threadIdx.x & 63;
    if (wid >= NN) return;
    float hv = fmaxf(acc[(long)wid * 64 + lane], 0.f);
    float4 w = ((const float4*)Wlin)[lane];
    float p0 = hv * w.x, p1 = hv * w.y, p2 = hv * w.z, p3 = hv * w.w;
    #pragma unroll
    for (int m = 32; m > 0; m >>= 1) {
        p0 += __shfl_xor(p0, m);
        p1 += __shfl_xor(p1, m);
        p2 += __shfl_xor(p2, m);
        p3 += __shfl_xor(p3, m);
    }
    if (lane == 0) {
        out4[4 * (long)wid + 0] = p0;
        out4[4 * (long)wid + 1] = p1;
        out4[4 * (long)wid + 2] = p2;
        out4[4 * (long)wid + 3] = p3;
    }
}

__global__ __launch_bounds__(256) void pf_accum(
    const int* __restrict__ pfi, const int* __restrict__ pfj,
    const float* __restrict__ pfa, const float* __restrict__ out4,
    float* __restrict__ Pb, float* __restrict__ Qp)
{
    int e = blockIdx.x * blockDim.x + threadIdx.x;
    if (e >= EPF) return;
    int i = pfi[e], j = pfj[e];
    float r = pfa[2 * (long)e], x = pfa[2 * (long)e + 1];
    float dn = r * r + x * x;
    float G = r / dn, B = -x / dn;
    float thi = out4[4 * (long)i + 1], thj = out4[4 * (long)j + 1];
    float Vi = fabsf(out4[4 * (long)i]), Vj = fabsf(out4[4 * (long)j]);
    float dlt = thj - thi;
    float cd = cosf(dlt), sd = sinf(dlt);
    float vv = Vi * Vj;
    atomicAdd(&Pb[i], vv * (G * cd + B * sd));
    atomicAdd(&Qp[i], vv * (G * sd - B * cd));
}

__global__ __launch_bounds__(256) void final_out(
    const float* __restrict__ out4, const float* __restrict__ cons,
    const float* __restrict__ xin, const float* __restrict__ Pb,
    const float* __restrict__ Qp, float* __restrict__ out)
{
    int n = blockIdx.x * blockDim.x + threadIdx.x;
    if (n >= NN) return;
    const float* c = cons + 7 * (long)n;
    float th = out4[4 * (long)n + 1];
    float V  = fabsf(out4[4 * (long)n + 0]);
    float o0 = csig(V, c[0], c[1]) / xin[4 * (long)n + 0];
    float o2 = csig(Pb[n], c[3], c[4]);
    float o3 = csig(Qp[n], c[5], c[6]);
    out[4 * (long)n + 0] = o0;
    out[4 * (long)n + 1] = th;
    out[4 * (long)n + 2] = o2;
    out[4 * (long)n + 3] = o3;
}

extern "C" void kernel_launch(void* const* d_in, const int* in_sizes, int n_in,
                              void* d_out, int out_size, void* d_ws, size_t ws_size,
                              hipStream_t stream) {
    const float* xin  = (const float*)d_in[0];
    const float* cons = (const float*)d_in[1];
    const int*   esrc = (const int*)d_in[2];
    const int*   edst = (const int*)d_in[3];
    const float* eatt = (const float*)d_in[4];
    const int*   pfi  = (const int*)d_in[5];
    const int*   pfj  = (const int*)d_in[6];
    const float* pfa  = (const float*)d_in[7];

    const float* Wlin;
    int wb;
    if (in_sizes[8] == 256) { Wlin = (const float*)d_in[8];  wb = 9; }
    else                    { Wlin = (const float*)d_in[26]; wb = 8; }
    const float* Wq0 = (const float*)d_in[wb + 0];
    const float* bq0 = (const float*)d_in[wb + 1];
    const float* Wk0 = (const float*)d_in[wb + 2];
    const float* bk0 = (const float*)d_in[wb + 3];
    const float* Wv0 = (const float*)d_in[wb + 4];
    const float* bv0 = (const float*)d_in[wb + 5];
    const float* We0 = (const float*)d_in[wb + 6];
    const float* Ws0 = (const float*)d_in[wb + 7];
    const float* bs0 = (const float*)d_in[wb + 8];
    const float* Wq1 = (const float*)d_in[wb + 9];
    const float* bq1 = (const float*)d_in[wb + 10];
    const float* Wk1 = (const float*)d_in[wb + 11];
    const float* bk1 = (const float*)d_in[wb + 12];
    const float* Wv1 = (const float*)d_in[wb + 13];
    const float* bv1 = (const float*)d_in[wb + 14];
    const float* We1 = (const float*)d_in[wb + 15];
    const float* Ws1 = (const float*)d_in[wb + 16];
    const float* bs1 = (const float*)d_in[wb + 17];

    // ---- workspace layout (~165 MB) ----
    float* w = (float*)d_ws;
    size_t off = 0;
    float* h1     = w + off; off += (size_t)NN * 64;
    float* acc    = w + off; off += (size_t)NN * 64;
    float* ug     = w + off; off += (size_t)NQ * 64;        // u then g (in-place)
    float* scal   = w + off; off += (size_t)NQ * 4;
    float* gm     = w + off; off += (size_t)NQ * 2;
    int*   rowst  = (int*)(w + off); off += NQ + 1;
    int*   cur    = (int*)(w + off); off += NQ;
    int*   bsum   = (int*)(w + off); off += 512;
    int*   elist  = (int*)(w + off); off += NEDGE;
    float* M2T    = w + off; off += (size_t)NREL * 64 * 64;
    float* vec4   = w + off; off += (size_t)NREL * 4 * 64;
    float* sclr   = w + off; off += NREL * 4;
    float* Wc0    = w + off; off += 4 * 4 * 64;
    float* Wc1    = w + off; off += 4 * 64 * 64;
    float* Pb     = w + off; off += NN;
    float* Qp     = w + off; off += NN;
    float* out4   = w + off; off += (size_t)NN * 4;
    if (ws_size < off * sizeof(float)) return;

    const int gaWBlocks  = (NQ + 3) / 4;
    const int nodeWaveBlks = (NN + 3) / 4;

    hipMemsetAsync(cur, 0, (size_t)NQ * 4, stream);
    hipMemsetAsync(Pb,  0, (size_t)NN * 4, stream);
    hipMemsetAsync(Qp,  0, (size_t)NN * 4, stream);

    combine_skip<4> <<<(4*4*64 + 255)/256, 256, 0, stream>>>(Ws0, Wc0);
    combine_skip<64><<<(4*64*64 + 255)/256, 256, 0, stream>>>(Ws1, Wc1);

    // CSR (static graph, shared by both layers)
    csr_count<<<(NEDGE + 255)/256, 256, 0, stream>>>(edst, cur);
    scan1<<<NB1, 1024, 0, stream>>>(cur, rowst, bsum);
    scan2<<<1, 512, 0, stream>>>(bsum);
    scan3<<<(NQ + 255)/256, 256, 0, stream>>>(bsum, rowst);
    hipMemsetAsync(cur, 0, (size_t)NQ * 4, stream);
    csr_fill<<<(NEDGE + 255)/256, 256, 0, stream>>>(edst, rowst, cur, elist);

    // ================= layer 0 (din=4, h = x) =================
    mk_m2t<4><<<(NREL*16 + 255)/256, 256, 0, stream>>>(Wk0, Wq0, M2T);
    mk_vecs<4><<<(NREL*16 + 255)/256, 256, 0, stream>>>(Wk0, Wq0, bq0, bk0, We0, vec4);
    mk_scl<<<1, 64, 0, stream>>>(bq0, bk0, We0, sclr);
    dstprep4<<<(NQ + 255)/256, 256, 0, stream>>>(xin, M2T, vec4, sclr, ug, scal);
    gfuse_t4<<<(NQ + 255)/256, 256, 0, stream>>>(xin, scal, esrc, eatt, rowst, elist, ug, gm);
    combine_g<4,1><<<TWAVES, 256, 0, stream>>>(xin, Wc0, bs0, Wv0, bv0, We0, ug, gm, rowst, h1);

    // ================= layer 1 (din=64, h = h1) =================
    mk_m2t<64><<<(NREL*64*64 + 255)/256, 256, 0, stream>>>(Wk1, Wq1, M2T);
    mk_vecs<64><<<(NREL*4*64 + 255)/256, 256, 0, stream>>>(Wk1, Wq1, bq1, bk1, We1, vec4);
    mk_scl<<<1, 64, 0, stream>>>(bq1, bk1, We1, sclr);
    dstprep_g<<<QWAVES, 256, 0, stream>>>(h1, M2T, vec4, sclr, ug, scal);
    gfuse_w<<<gaWBlocks, 256, 0, stream>>>(h1, scal, esrc, eatt, rowst, elist, ug, gm);
    combine_g<64,0><<<TWAVES, 256, 0, stream>>>(h1, Wc1, bs1, Wv1, bv1, We1, ug, gm, rowst, acc);

    // ================= head + power flow + final =================
    head<<<nodeWaveBlks, 256, 0, stream>>>(acc, Wlin, out4);
    pf_accum<<<(EPF + 255)/256, 256, 0, stream>>>(pfi, pfj, pfa, out4, Pb, Qp);
    final_out<<<(NQ < NN ? (NN + 255)/256 : (NN + 255)/256), 256, 0, stream>>>(out4, cons, xin, Pb, Qp, (float*)d_out);
}

// Round 12
// 722.190 us; speedup vs baseline: 4.4967x; 1.1735x over previous
//
#include <hip/hip_runtime.h>
#include <hip/hip_bf16.h>

#define NREL 14
#define NE     100000
#define NEDGE  (NREL*NE)
#define NN     100000
#define EPF    800000
#define NQ     370000                 // sum of dst-range sizes over relations
#define NB1    ((NQ + 1023) / 1024)   // scan blocks = 362
#define QWAVES 5786                   // sum ceil(nd/64) (also GEMM blocks)
#define TWAVES 1564                   // sum ceil(typesize/64)

__device__ __constant__ int d_dlo[NREL]   = {10000,30000,70000,30000,70000,70000,0,0,0,10000,30000,10000,30000,70000};
__device__ __constant__ int d_qoff[NREL+1]= {0,20000,60000,90000,130000,160000,190000,200000,210000,220000,240000,280000,300000,340000,370000};
__device__ __constant__ int d_qwoff[NREL+1]={0,313,938,1407,2032,2501,2970,3127,3284,3441,3754,4379,4692,5317,5786};
__device__ __constant__ int d_trel[4][4]  = {{6,7,8,-1},{0,9,11,-1},{1,3,10,12},{2,4,5,13}};
__device__ __constant__ int d_ntrel[4]    = {3,3,4,4};
__device__ __constant__ int d_tbase[5]    = {0,10000,30000,70000,100000};
__device__ __constant__ int d_twoff[5]    = {0,157,470,1095,1564};

__device__ __forceinline__ float csig(float v, float lo, float hi) {
    float mid = 0.5f * (lo + hi);
    float s = 1.0f / (1.0f + expf(-0.1f * (v - mid)));
    return (s - 0.5f) * (hi - lo) + mid;
}

// ==================== tiled-GEMM building blocks ===========================
template<int K>
__device__ __forceinline__ void stage_in(
    float* sIn, const float* __restrict__ src, int l0, int n, int tid)
{
    if (K == 4) {
        if (tid < 64) {
            int lcl = min(l0 + tid, n - 1);
            float4 v = *(const float4*)(src + (long)lcl * 4);
            sIn[0 * 64 + tid] = v.x; sIn[1 * 64 + tid] = v.y;
            sIn[2 * 64 + tid] = v.z; sIn[3 * 64 + tid] = v.w;
        }
    } else {
        int row = tid >> 2, q = tid & 3;
        int lcl = min(l0 + row, n - 1);
        const float* p = src + (long)lcl * 64 + q * 16;
        #pragma unroll
        for (int kk = 0; kk < 4; ++kk) {
            float4 v = *(const float4*)(p + kk * 4);
            int k = q * 16 + kk * 4;
            sIn[(k + 0) * 64 + row] = v.x;
            sIn[(k + 1) * 64 + row] = v.y;
            sIn[(k + 2) * 64 + row] = v.z;
            sIn[(k + 3) * 64 + row] = v.w;
        }
    }
}

template<int K>
__device__ __forceinline__ void stage_w(
    float* sW, const float* __restrict__ src, int tid)
{
    for (int i = tid * 4; i < K * 64; i += 1024)
        *(float4*)(sW + i) = *(const float4*)(src + i);
}

template<int K>
__device__ __forceinline__ void mma_t(
    float acc[4][4], const float* sIn, const float* sW, int r0, int c0)
{
    for (int k = 0; k < K; ++k) {
        float4 a = *(const float4*)(sIn + k * 64 + r0);
        float4 b = *(const float4*)(sW + k * 64 + c0);
        acc[0][0] = fmaf(a.x, b.x, acc[0][0]);
        acc[0][1] = fmaf(a.x, b.y, acc[0][1]);
        acc[0][2] = fmaf(a.x, b.z, acc[0][2]);
        acc[0][3] = fmaf(a.x, b.w, acc[0][3]);
        acc[1][0] = fmaf(a.y, b.x, acc[1][0]);
        acc[1][1] = fmaf(a.y, b.y, acc[1][1]);
        acc[1][2] = fmaf(a.y, b.z, acc[1][2]);
        acc[1][3] = fmaf(a.y, b.w, acc[1][3]);
        acc[2][0] = fmaf(a.z, b.x, acc[2][0]);
        acc[2][1] = fmaf(a.z, b.y, acc[2][1]);
        acc[2][2] = fmaf(a.z, b.z, acc[2][2]);
        acc[2][3] = fmaf(a.z, b.w, acc[2][3]);
        acc[3][0] = fmaf(a.w, b.x, acc[3][0]);
        acc[3][1] = fmaf(a.w, b.y, acc[3][1]);
        acc[3][2] = fmaf(a.w, b.z, acc[3][2]);
        acc[3][3] = fmaf(a.w, b.w, acc[3][3]);
    }
}

// ---- combined skip weights: Wc[t] = sum_{r: dst_type==t} Ws[r] -------------
template<int DIN>
__global__ __launch_bounds__(256) void combine_skip(
    const float* __restrict__ Ws, float* __restrict__ Wc)
{
    int tid = blockIdx.x * blockDim.x + threadIdx.x;
    if (tid >= 4 * DIN * 64) return;
    int t = tid / (DIN * 64), o = tid % (DIN * 64);
    float s = 0.f;
    for (int ri = 0; ri < d_ntrel[t]; ++ri) s += Ws[d_trel[t][ri] * DIN * 64 + o];
    Wc[tid] = s;
}

// ---- relation prep ---------------------------------------------------------
template<int DIN>
__global__ __launch_bounds__(256) void mk_m2t(
    const float* __restrict__ Wk, const float* __restrict__ Wq,
    float* __restrict__ M2T)
{
    int tid = blockIdx.x * blockDim.x + threadIdx.x;
    if (tid >= NREL * DIN * DIN) return;
    int r = tid / (DIN * DIN), rem = tid % (DIN * DIN);
    int i = rem / DIN, j = rem % DIN;
    const float* wki = Wk + (long)r * DIN * 64 + i * 64;
    const float* wqj = Wq + (long)r * DIN * 64 + j * 64;
    float s = 0.f;
    for (int c = 0; c < 64; ++c) s = fmaf(wki[c], wqj[c], s);
    M2T[(long)r * DIN * DIN + j * DIN + i] = s;
}

// vec4[r][k][i]: k=0: Wk bq (u init); k=1: Wq we0; k=2: Wq we1; k=3: Wq bk
template<int DIN>
__global__ __launch_bounds__(256) void mk_vecs(
    const float* __restrict__ Wk, const float* __restrict__ Wq,
    const float* __restrict__ bq, const float* __restrict__ bk,
    const float* __restrict__ We, float* __restrict__ vec4)
{
    int tid = blockIdx.x * blockDim.x + threadIdx.x;
    if (tid >= NREL * 4 * DIN) return;
    int r = tid / (4 * DIN), rem = tid % (4 * DIN);
    int k = rem / DIN, i = rem % DIN;
    const float* row; const float* v;
    if (k == 0) { row = Wk + (long)r * DIN * 64 + i * 64; v = bq + r * 64; }
    else {
        row = Wq + (long)r * DIN * 64 + i * 64;
        v = (k == 1) ? We + r * 128 : (k == 2) ? We + r * 128 + 64 : bk + r * 64;
    }
    float s = 0.f;
    for (int c = 0; c < 64; ++c) s = fmaf(row[c], v[c], s);
    vec4[tid] = s;
}

// scl[r] = (bq.we0, bq.we1, bk.bq, 0)
__global__ __launch_bounds__(64) void mk_scl(
    const float* __restrict__ bq, const float* __restrict__ bk,
    const float* __restrict__ We, float* __restrict__ scl)
{
    int r = blockIdx.x * blockDim.x + threadIdx.x;
    if (r >= NREL) return;
    float s0 = 0.f, s1 = 0.f, sb = 0.f;
    for (int c = 0; c < 64; ++c) {
        float b = bq[r * 64 + c];
        s0 = fmaf(b, We[r * 128 + c], s0);
        s1 = fmaf(b, We[r * 128 + 64 + c], s1);
        sb = fmaf(b, bk[r * 64 + c], sb);
    }
    scl[4 * r] = s0; scl[4 * r + 1] = s1; scl[4 * r + 2] = sb; scl[4 * r + 3] = 0.f;
}

// ---- layer0 per-dst prep (din=4): u float4 + scal -------------------------
__global__ __launch_bounds__(256) void dstprep4(
    const float* __restrict__ h, const float* __restrict__ M2T,
    const float* __restrict__ vec4, const float* __restrict__ scl,
    float* __restrict__ ug, float* __restrict__ scal)
{
    int idx = blockIdx.x * blockDim.x + threadIdx.x;
    if (idx >= NQ) return;
    int r = 0;
    while (r < NREL - 1 && idx >= d_qoff[r + 1]) ++r;
    int node = d_dlo[r] + (idx - d_qoff[r]);
    float4 hv = ((const float4*)h)[node];
    const float* m2 = M2T + (long)r * 16;
    const float* vb = vec4 + (long)r * 16;
    float u[4];
    #pragma unroll
    for (int c = 0; c < 4; ++c)
        u[c] = vb[c] + hv.x * m2[c] + hv.y * m2[4 + c] + hv.z * m2[8 + c] + hv.w * m2[12 + c];
    float sc0 = scl[4*r]   + hv.x*vb[4]  + hv.y*vb[5]  + hv.z*vb[6]  + hv.w*vb[7];
    float sc1 = scl[4*r+1] + hv.x*vb[8]  + hv.y*vb[9]  + hv.z*vb[10] + hv.w*vb[11];
    float scb = scl[4*r+2] + hv.x*vb[12] + hv.y*vb[13] + hv.z*vb[14] + hv.w*vb[15];
    ((float4*)ug)[idx] = make_float4(u[0], u[1], u[2], u[3]);
    ((float4*)scal)[idx] = make_float4(sc0, sc1, scb, 0.f);
}

// ---- layer1 per-dst prep: tiled GEMM u = M2 h_d + bias; + scal fold -------
__global__ __launch_bounds__(256) void dstprep_g(
    const float* __restrict__ h, const float* __restrict__ M2T,
    const float* __restrict__ vec4, const float* __restrict__ scl,
    float* __restrict__ ug, float* __restrict__ scal)
{
    __shared__ float sIn[64 * 64];
    __shared__ float sW[64 * 64];
    int blk = blockIdx.x, tid = threadIdx.x;
    int r = 0;
    while (r < NREL - 1 && blk >= d_qwoff[r + 1]) ++r;
    int l0 = (blk - d_qwoff[r]) * 64;
    int nd = d_qoff[r + 1] - d_qoff[r];
    stage_in<64>(sIn, h + (long)d_dlo[r] * 64, l0, nd, tid);
    stage_w<64>(sW, M2T + (long)r * 4096, tid);
    __syncthreads();
    int tx = tid & 15, ty = tid >> 4;
    int r0 = ty * 4, c0 = tx * 4;
    float4 bias = *(const float4*)(vec4 + (long)r * 256 + c0);
    float acc[4][4];
    #pragma unroll
    for (int i = 0; i < 4; ++i) {
        acc[i][0] = bias.x; acc[i][1] = bias.y; acc[i][2] = bias.z; acc[i][3] = bias.w;
    }
    mma_t<64>(acc, sIn, sW, r0, c0);
    #pragma unroll
    for (int i = 0; i < 4; ++i) {
        int lr = l0 + r0 + i;
        if (lr < nd)
            *(float4*)(ug + (long)(d_qoff[r] + lr) * 64 + c0) =
                make_float4(acc[i][0], acc[i][1], acc[i][2], acc[i][3]);
    }
    // per-dst scalars from the staged h tile (wave 0)
    if (tid < 64) {
        const float* w1p = vec4 + (long)r * 256 + 64;
        const float* w2p = vec4 + (long)r * 256 + 128;
        const float* w3p = vec4 + (long)r * 256 + 192;
        float s0 = 0.f, s1 = 0.f, s2 = 0.f;
        for (int k = 0; k < 64; ++k) {
            float hv = sIn[k * 64 + tid];
            s0 = fmaf(hv, w1p[k], s0);
            s1 = fmaf(hv, w2p[k], s1);
            s2 = fmaf(hv, w3p[k], s2);
        }
        int lr = l0 + tid;
        if (lr < nd)
            ((float4*)scal)[d_qoff[r] + lr] =
                make_float4(s0 + scl[4*r], s1 + scl[4*r+1], s2 + scl[4*r+2], 0.f);
    }
}

// ---- CSR build (static graph) ---------------------------------------------
__global__ __launch_bounds__(256) void csr_count(
    const int* __restrict__ edst, int* __restrict__ cur)
{
    int tid = blockIdx.x * blockDim.x + threadIdx.x;
    if (tid >= NEDGE) return;
    int r = tid / NE;
    atomicAdd(&cur[d_qoff[r] + edst[tid] - d_dlo[r]], 1);
}

__global__ __launch_bounds__(1024) void scan1(
    const int* __restrict__ cur, int* __restrict__ rowst, int* __restrict__ bsum)
{
    __shared__ int s[1024];
    int t = threadIdx.x, g = blockIdx.x * 1024 + t;
    s[t] = g < NQ ? cur[g] : 0;
    __syncthreads();
    for (int o = 1; o < 1024; o <<= 1) {
        int x = t >= o ? s[t - o] : 0;
        __syncthreads();
        s[t] += x;
        __syncthreads();
    }
    if (g < NQ) rowst[g + 1] = s[t];
    if (t == 1023) bsum[blockIdx.x] = s[1023];
}

__global__ __launch_bounds__(512) void scan2(int* __restrict__ bsum)
{
    __shared__ int s[512];
    int t = threadIdx.x;
    s[t] = t < NB1 ? bsum[t] : 0;
    __syncthreads();
    for (int o = 1; o < 512; o <<= 1) {
        int x = t >= o ? s[t - o] : 0;
        __syncthreads();
        s[t] += x;
        __syncthreads();
    }
    if (t < NB1) bsum[t] = (t == 0) ? 0 : s[t - 1];
}

__global__ __launch_bounds__(256) void scan3(
    const int* __restrict__ bsum, int* __restrict__ rowst)
{
    int g = blockIdx.x * blockDim.x + threadIdx.x;
    if (g == 0) rowst[0] = 0;
    if (g < NQ) rowst[g + 1] += bsum[g >> 10];
}

__global__ __launch_bounds__(256) void csr_fill(
    const int* __restrict__ edst, const int* __restrict__ rowst,
    int* __restrict__ cur, int* __restrict__ elist)
{
    int tid = blockIdx.x * blockDim.x + threadIdx.x;
    if (tid >= NEDGE) return;
    int r = tid / NE;
    int idx = d_qoff[r] + edst[tid] - d_dlo[r];
    int pos = rowst[idx] + atomicAdd(&cur[idx], 1);
    elist[pos] = tid;
}

// ---- fused edge phase, layer 0: thread/idx, branchless online softmax -----
__global__ __launch_bounds__(256) void gfuse_t4(
    const float* __restrict__ h, const float* __restrict__ scal,
    const int* __restrict__ esrc, const float* __restrict__ eattr,
    const int* __restrict__ rowst, const int* __restrict__ elist,
    float* __restrict__ ug, float* __restrict__ gm)
{
    int idx = blockIdx.x * blockDim.x + threadIdx.x;
    if (idx >= NQ) return;
    int e0 = rowst[idx], e1 = rowst[idx + 1];
    if (e0 == e1) {
        ((float4*)ug)[idx] = make_float4(0.f, 0.f, 0.f, 0.f);
        gm[2 * (long)idx] = 0.f; gm[2 * (long)idx + 1] = 0.f;
        return;
    }
    float4 u = ((const float4*)ug)[idx];
    float4 sc = ((const float4*)scal)[idx];
    float m = -3.4e38f, den = 0.f, m0 = 0.f, m1 = 0.f;
    float gx = 0.f, gy = 0.f, gz = 0.f, gw = 0.f;
    for (int e = e0; e < e1; ++e) {
        int eid = elist[e];
        float4 hs = ((const float4*)h)[esrc[eid]];
        float2 ea = *(const float2*)(eattr + 2 * (long)eid);
        float alpha = 0.125f * (hs.x*u.x + hs.y*u.y + hs.z*u.z + hs.w*u.w
                                + sc.z + ea.x * sc.x + ea.y * sc.y);
        float nm = fmaxf(m, alpha);
        float s = expf(m - nm);
        float a = expf(alpha - nm);
        m = nm;
        den = den * s + a;
        gx = gx * s + a * hs.x; gy = gy * s + a * hs.y;
        gz = gz * s + a * hs.z; gw = gw * s + a * hs.w;
        m0 = m0 * s + a * ea.x; m1 = m1 * s + a * ea.y;
    }
    float inv = 1.f / (den + 1e-16f);
    ((float4*)ug)[idx] = make_float4(gx*inv, gy*inv, gz*inv, gw*inv);
    gm[2 * (long)idx] = m0 * inv; gm[2 * (long)idx + 1] = m1 * inv;
}

// ---- fused edge phase, layer 1: QUARTER-wave (16 lanes) per dst row -------
// 4 rows/wave; u,h as float4/lane; 4-stage shuffle; branchless online SM
__global__ __launch_bounds__(256) void gfuse_q(
    const float* __restrict__ h, const float* __restrict__ scal,
    const int* __restrict__ esrc, const float* __restrict__ eattr,
    const int* __restrict__ rowst, const int* __restrict__ elist,
    float* __restrict__ ug, float* __restrict__ gm)
{
    int idx = (blockIdx.x * blockDim.x + threadIdx.x) >> 4;   // one dst row / 16 lanes
    int ql  = threadIdx.x & 15;
    if (idx >= NQ) return;
    int e0 = rowst[idx], e1 = rowst[idx + 1];
    long ubase = (long)idx * 64 + ql * 4;
    if (e0 == e1) {
        *(float4*)(ug + ubase) = make_float4(0.f, 0.f, 0.f, 0.f);
        if (ql == 0) { gm[2*(long)idx] = 0.f; gm[2*(long)idx+1] = 0.f; }
        return;
    }
    float4 u = *(const float4*)(ug + ubase);
    float4 sc = ((const float4*)scal)[idx];
    float m = -3.4e38f, den = 0.f, m0 = 0.f, m1 = 0.f;
    float4 g = make_float4(0.f, 0.f, 0.f, 0.f);
    for (int e = e0; e < e1; ++e) {
        int eid = elist[e];
        int s = esrc[eid];
        float2 ea = *(const float2*)(eattr + 2 * (long)eid);
        float4 hs = *(const float4*)(h + (long)s * 64 + ql * 4);
        float p = hs.x*u.x + hs.y*u.y + hs.z*u.z + hs.w*u.w;
        p += __shfl_xor(p, 1);
        p += __shfl_xor(p, 2);
        p += __shfl_xor(p, 4);
        p += __shfl_xor(p, 8);
        float alpha = 0.125f * (p + sc.z + ea.x * sc.x + ea.y * sc.y);
        float nm = fmaxf(m, alpha);
        float s0 = expf(m - nm);
        float a  = expf(alpha - nm);
        m = nm;
        den = den * s0 + a;
        g.x = g.x * s0 + a * hs.x;
        g.y = g.y * s0 + a * hs.y;
        g.z = g.z * s0 + a * hs.z;
        g.w = g.w * s0 + a * hs.w;
        m0 = m0 * s0 + a * ea.x;
        m1 = m1 * s0 + a * ea.y;
    }
    float inv = 1.f / (den + 1e-16f);
    *(float4*)(ug + ubase) = make_float4(g.x*inv, g.y*inv, g.z*inv, g.w*inv);
    if (ql == 0) { gm[2*(long)idx] = m0 * inv; gm[2*(long)idx+1] = m1 * inv; }
}

// ---- combine (tiled): out = h@Wc + sum_r [ g@Wv + rank-1 terms ] ----------
template<int K, int RELU>
__global__ __launch_bounds__(256) void combine_g(
    const float* __restrict__ h, const float* __restrict__ Wc,
    const float* __restrict__ bs, const float* __restrict__ Wv,
    const float* __restrict__ bv, const float* __restrict__ We,
    const float* __restrict__ ug, const float* __restrict__ gm,
    const int* __restrict__ rowst, float* __restrict__ outp)
{
    __shared__ float sIn[K * 64];
    __shared__ float sW[K * 64];
    __shared__ float sHe[64], sG0[64], sG1[64];
    int blk = blockIdx.x, tid = threadIdx.x;
    int t = 0;
    while (t < 3 && blk >= d_twoff[t + 1]) ++t;
    int l0 = (blk - d_twoff[t]) * 64;
    int nt = d_tbase[t + 1] - d_tbase[t];
    int tx = tid & 15, ty = tid >> 4;
    int r0 = ty * 4, c0 = tx * 4;
    float acc[4][4];
    #pragma unroll
    for (int i = 0; i < 4; ++i) {
        acc[i][0] = 0.f; acc[i][1] = 0.f; acc[i][2] = 0.f; acc[i][3] = 0.f;
    }
    stage_in<K>(sIn, h + (long)d_tbase[t] * K, l0, nt, tid);
    stage_w<K>(sW, Wc + (long)t * K * 64, tid);
    __syncthreads();
    mma_t<K>(acc, sIn, sW, r0, c0);
    int nr = d_ntrel[t];
    for (int ri = 0; ri < nr; ++ri) {
        int rr = d_trel[t][ri];
        __syncthreads();
        stage_in<K>(sIn, ug + (long)d_qoff[rr] * K, l0, nt, tid);
        stage_w<K>(sW, Wv + (long)rr * K * 64, tid);
        if (tid < 64) {
            int lcl = min(l0 + tid, nt - 1);
            long idx = d_qoff[rr] + lcl;
            sHe[tid] = (rowst[idx + 1] > rowst[idx]) ? 1.f : 0.f;
            sG0[tid] = gm[2 * idx];
            sG1[tid] = gm[2 * idx + 1];
        }
        __syncthreads();
        mma_t<K>(acc, sIn, sW, r0, c0);
        float4 bsr = *(const float4*)(bs + rr * 64 + c0);
        float4 bvr = *(const float4*)(bv + rr * 64 + c0);
        float4 w0  = *(const float4*)(We + rr * 128 + c0);
        float4 w1  = *(const float4*)(We + rr * 128 + 64 + c0);
        #pragma unroll
        for (int i = 0; i < 4; ++i) {
            float he = sHe[r0 + i], g0 = sG0[r0 + i], g1 = sG1[r0 + i];
            acc[i][0] += bsr.x + he * bvr.x + g0 * w0.x + g1 * w1.x;
            acc[i][1] += bsr.y + he * bvr.y + g0 * w0.y + g1 * w1.y;
            acc[i][2] += bsr.z + he * bvr.z + g0 * w0.z + g1 * w1.z;
            acc[i][3] += bsr.w + he * bvr.w + g0 * w0.w + g1 * w1.w;
        }
    }
    #pragma unroll
    for (int i = 0; i < 4; ++i) {
        int lr = l0 + r0 + i;
        if (lr < nt) {
            float4 v = make_float4(acc[i][0], acc[i][1], acc[i][2], acc[i][3]);
            if (RELU) {
                v.x = fmaxf(v.x, 0.f); v.y = fmaxf(v.y, 0.f);
                v.z = fmaxf(v.z, 0.f); v.w = fmaxf(v.w, 0.f);
            }
            *(float4*)(outp + (long)(d_tbase[t] + lr) * 64 + c0) = v;
        }
    }
}

// ---- head / power flow / final --------------------------------------------
__global__ __launch_bounds__(256) void head(
    const float* __restrict__ acc, const float* __restrict__ Wlin,
    float* __restrict__ out4)
{
    int wid  = (blockIdx.x * blockDim.x + threadIdx.x) >> 6;
    int lane = threadIdx.x & 63;
    if (wid >= NN) return;
    float hv = fmaxf(acc[(long)wid * 64 + lane], 0.f);
    float4 w = ((const float4*)Wlin)[lane];
    float p0 = hv * w.x, p1 = hv * w.y, p2 = hv * w.z, p3 = hv * w.w;
    #pragma unroll
    for (int m = 32; m > 0; m >>= 1) {
        p0 += __shfl_xor(p0, m);
        p1 += __shfl_xor(p1, m);
        p2 += __shfl_xor(p2, m);
        p3 += __shfl_xor(p3, m);
    }
    if (lane == 0) {
        out4[4 * (long)wid + 0] = p0;
        out4[4 * (long)wid + 1] = p1;
        out4[4 * (long)wid + 2] = p2;
        out4[4 * (long)wid + 3] = p3;
    }
}

__global__ __launch_bounds__(256) void pf_accum(
    const int* __restrict__ pfi, const int* __restrict__ pfj,
    const float* __restrict__ pfa, const float* __restrict__ out4,
    float* __restrict__ Pb, float* __restrict__ Qp)
{
    int e = blockIdx.x * blockDim.x + threadIdx.x;
    if (e >= EPF) return;
    int i = pfi[e], j = pfj[e];
    float r = pfa[2 * (long)e], x = pfa[2 * (long)e + 1];
    float dn = r * r + x * x;
    float G = r / dn, B = -x / dn;
    float thi = out4[4 * (long)i + 1], thj = out4[4 * (long)j + 1];
    float Vi = fabsf(out4[4 * (long)i]), Vj = fabsf(out4[4 * (long)j]);
    float dlt = thj - thi;
    float cd = cosf(dlt), sd = sinf(dlt);
    float vv = Vi * Vj;
    atomicAdd(&Pb[i], vv * (G * cd + B * sd));
    atomicAdd(&Qp[i], vv * (G * sd - B * cd));
}

__global__ __launch_bounds__(256) void final_out(
    const float* __restrict__ out4, const float* __restrict__ cons,
    const float* __restrict__ xin, const float* __restrict__ Pb,
    const float* __restrict__ Qp, float* __restrict__ out)
{
    int n = blockIdx.x * blockDim.x + threadIdx.x;
    if (n >= NN) return;
    const float* c = cons + 7 * (long)n;
    float th = out4[4 * (long)n + 1];
    float V  = fabsf(out4[4 * (long)n + 0]);
    float o0 = csig(V, c[0], c[1]) / xin[4 * (long)n + 0];
    float o2 = csig(Pb[n], c[3], c[4]);
    float o3 = csig(Qp[n], c[5], c[6]);
    out[4 * (long)n + 0] = o0;
    out[4 * (long)n + 1] = th;
    out[4 * (long)n + 2] = o2;
    out[4 * (long)n + 3] = o3;
}

extern "C" void kernel_launch(void* const* d_in, const int* in_sizes, int n_in,
                              void* d_out, int out_size, void* d_ws, size_t ws_size,
                              hipStream_t stream) {
    const float* xin  = (const float*)d_in[0];
    const float* cons = (const float*)d_in[1];
    const int*   esrc = (const int*)d_in[2];
    const int*   edst = (const int*)d_in[3];
    const float* eatt = (const float*)d_in[4];
    const int*   pfi  = (const int*)d_in[5];
    const int*   pfj  = (const int*)d_in[6];
    const float* pfa  = (const float*)d_in[7];

    const float* Wlin;
    int wb;
    if (in_sizes[8] == 256) { Wlin = (const float*)d_in[8];  wb = 9; }
    else                    { Wlin = (const float*)d_in[26]; wb = 8; }
    const float* Wq0 = (const float*)d_in[wb + 0];
    const float* bq0 = (const float*)d_in[wb + 1];
    const float* Wk0 = (const float*)d_in[wb + 2];
    const float* bk0 = (const float*)d_in[wb + 3];
    const float* Wv0 = (const float*)d_in[wb + 4];
    const float* bv0 = (const float*)d_in[wb + 5];
    const float* We0 = (const float*)d_in[wb + 6];
    const float* Ws0 = (const float*)d_in[wb + 7];
    const float* bs0 = (const float*)d_in[wb + 8];
    const float* Wq1 = (const float*)d_in[wb + 9];
    const float* bq1 = (const float*)d_in[wb + 10];
    const float* Wk1 = (const float*)d_in[wb + 11];
    const float* bk1 = (const float*)d_in[wb + 12];
    const float* Wv1 = (const float*)d_in[wb + 13];
    const float* bv1 = (const float*)d_in[wb + 14];
    const float* We1 = (const float*)d_in[wb + 15];
    const float* Ws1 = (const float*)d_in[wb + 16];
    const float* bs1 = (const float*)d_in[wb + 17];

    // ---- workspace layout (~165 MB) ----
    float* w = (float*)d_ws;
    size_t off = 0;
    float* h1     = w + off; off += (size_t)NN * 64;
    float* acc    = w + off; off += (size_t)NN * 64;
    float* ug     = w + off; off += (size_t)NQ * 64;        // u then g (in-place)
    float* scal   = w + off; off += (size_t)NQ * 4;
    float* gm     = w + off; off += (size_t)NQ * 2;
    int*   rowst  = (int*)(w + off); off += NQ + 1;
    int*   cur    = (int*)(w + off); off += NQ;
    int*   bsum   = (int*)(w + off); off += 512;
    int*   elist  = (int*)(w + off); off += NEDGE;
    float* M2T    = w + off; off += (size_t)NREL * 64 * 64;
    float* vec4   = w + off; off += (size_t)NREL * 4 * 64;
    float* sclr   = w + off; off += NREL * 4;
    float* Wc0    = w + off; off += 4 * 4 * 64;
    float* Wc1    = w + off; off += 4 * 64 * 64;
    float* Pb     = w + off; off += NN;
    float* Qp     = w + off; off += NN;
    float* out4   = w + off; off += (size_t)NN * 4;
    if (ws_size < off * sizeof(float)) return;

    const int nodeWaveBlks = (NN + 3) / 4;
    const int gqBlocks = ((size_t)NQ * 16 + 255) / 256;     // quarter-wave grid

    hipMemsetAsync(cur, 0, (size_t)NQ * 4, stream);
    hipMemsetAsync(Pb,  0, (size_t)NN * 4, stream);
    hipMemsetAsync(Qp,  0, (size_t)NN * 4, stream);

    combine_skip<4> <<<(4*4*64 + 255)/256, 256, 0, stream>>>(Ws0, Wc0);
    combine_skip<64><<<(4*64*64 + 255)/256, 256, 0, stream>>>(Ws1, Wc1);

    // CSR (static graph, shared by both layers)
    csr_count<<<(NEDGE + 255)/256, 256, 0, stream>>>(edst, cur);
    scan1<<<NB1, 1024, 0, stream>>>(cur, rowst, bsum);
    scan2<<<1, 512, 0, stream>>>(bsum);
    scan3<<<(NQ + 255)/256, 256, 0, stream>>>(bsum, rowst);
    hipMemsetAsync(cur, 0, (size_t)NQ * 4, stream);
    csr_fill<<<(NEDGE + 255)/256, 256, 0, stream>>>(edst, rowst, cur, elist);

    // ================= layer 0 (din=4, h = x) =================
    mk_m2t<4><<<(NREL*16 + 255)/256, 256, 0, stream>>>(Wk0, Wq0, M2T);
    mk_vecs<4><<<(NREL*16 + 255)/256, 256, 0, stream>>>(Wk0, Wq0, bq0, bk0, We0, vec4);
    mk_scl<<<1, 64, 0, stream>>>(bq0, bk0, We0, sclr);
    dstprep4<<<(NQ + 255)/256, 256, 0, stream>>>(xin, M2T, vec4, sclr, ug, scal);
    gfuse_t4<<<(NQ + 255)/256, 256, 0, stream>>>(xin, scal, esrc, eatt, rowst, elist, ug, gm);
    combine_g<4,1><<<TWAVES, 256, 0, stream>>>(xin, Wc0, bs0, Wv0, bv0, We0, ug, gm, rowst, h1);

    // ================= layer 1 (din=64, h = h1) =================
    mk_m2t<64><<<(NREL*64*64 + 255)/256, 256, 0, stream>>>(Wk1, Wq1, M2T);
    mk_vecs<64><<<(NREL*4*64 + 255)/256, 256, 0, stream>>>(Wk1, Wq1, bq1, bk1, We1, vec4);
    mk_scl<<<1, 64, 0, stream>>>(bq1, bk1, We1, sclr);
    dstprep_g<<<QWAVES, 256, 0, stream>>>(h1, M2T, vec4, sclr, ug, scal);
    gfuse_q<<<gqBlocks, 256, 0, stream>>>(h1, scal, esrc, eatt, rowst, elist, ug, gm);
    combine_g<64,0><<<TWAVES, 256, 0, stream>>>(h1, Wc1, bs1, Wv1, bv1, We1, ug, gm, rowst, acc);

    // ================= head + power flow + final =================
    head<<<nodeWaveBlks, 256, 0, stream>>>(acc, Wlin, out4);
    pf_accum<<<(EPF + 255)/256, 256, 0, stream>>>(pfi, pfj, pfa, out4, Pb, Qp);
    final_out<<<(NN + 255)/256, 256, 0, stream>>>(out4, cons, xin, Pb, Qp, (float*)d_out);
}